// Round 2
// baseline (203.974 us; speedup 1.0000x reference)
//
#include <hip/hip_runtime.h>
#include <math.h>

// R12: R11 + end-of-kernel vmcnt(0) drain in flash (suspected R11 fault:
// tail-clamped stages left global_load_lds in flight at s_endpgm -> LDS
// DMA lands after workgroup teardown -> corruption/fault -> container die).
// Flash structure (R11): counted-vmcnt pipeline (T3+T4) + balanced chunks.
//  * 512-thread blocks (8 waves x 16 q-rows = 128 q-rows/block), 512 blocks.
//  * K staged 3 ahead / V staged 2 ahead, both triple-buffered (48KB LDS,
//    2 blocks/CU = 16 waves/CU). Tail stages clamped so every iter issues
//    exactly 2 gl_lds16/wave -> barrier is s_waitcnt vmcnt(2) lgkmcnt(0) +
//    s_barrier: last iter's loads stay in flight across the barrier
//    (removes the per-iter vmcnt(0) drain stall).
//  * chunk pairing c = g<8 ? 15-g : g-8 -> every CU's 2 blocks sum to 34
//    iters (was 52..80 across CUs). bn mapping (XCD L2 locality) unchanged.
// GEMMs (m97 + xor-swizzled LDS, R8-verified) unchanged.
// Layouts (verified R2-R9, absmax 7.8e-3):
//   x32 A-frag: m=lane&15, k=(lane>>4)*8+j ; B-frag: n=lane&15, k=(lane>>4)*8+j
//   x16 A/B-frag: idx=lane&15, k=(lane>>4)*4+j
//   C/D (all 16x16): col=lane&15, row=(lane>>4)*4+reg

#define SS_ 2048
#define DD_ 1024
#define NH_ 16
#define BN_ 32
#define BS_ 4096

typedef __bf16 bf16x8 __attribute__((ext_vector_type(8)));
typedef __bf16 bf16x4 __attribute__((ext_vector_type(4)));
typedef short shortx4 __attribute__((ext_vector_type(4)));
typedef float floatx4 __attribute__((ext_vector_type(4)));
typedef unsigned short ushortx4 __attribute__((ext_vector_type(4)));

__device__ __forceinline__ unsigned short f2bf(float f) {
    union { float f; unsigned u; } v; v.f = f;
    unsigned r = v.u + 0x7FFFu + ((v.u >> 16) & 1u);   // RNE
    return (unsigned short)(r >> 16);
}

__device__ __forceinline__ floatx4 mfma_pv(bf16x4 a, bf16x4 b, floatx4 c) {
#if __has_builtin(__builtin_amdgcn_mfma_f32_16x16x16_bf16)
    return __builtin_amdgcn_mfma_f32_16x16x16_bf16(a, b, c, 0, 0, 0);
#else
    return __builtin_amdgcn_mfma_f32_16x16x16bf16_1k(
        __builtin_bit_cast(shortx4, a), __builtin_bit_cast(shortx4, b), c, 0, 0, 0);
#endif
}

__device__ __forceinline__ void gl_lds16(const unsigned short* g, unsigned short* l) {
    __builtin_amdgcn_global_load_lds(
        (const __attribute__((address_space(1))) unsigned int*)g,
        (__attribute__((address_space(3))) unsigned int*)l, 16, 0, 0);
}

// ---------- K0a: cast resid + WQ/WK/WV to bf16 ----------
__global__ __launch_bounds__(256) void cast_bf16_kernel(
    const float* __restrict__ resid, const float* __restrict__ WQ,
    const float* __restrict__ WK, const float* __restrict__ WV,
    unsigned short* __restrict__ residB, unsigned short* __restrict__ WQb,
    unsigned short* __restrict__ WKb, unsigned short* __restrict__ WVb)
{
    const int z = blockIdx.y;
    if (z > 0 && blockIdx.x >= 1024) return;
    const float* src = (z == 0) ? resid : (z == 1) ? WQ : (z == 2) ? WK : WV;
    unsigned short* dst = (z == 0) ? residB : (z == 1) ? WQb : (z == 2) ? WKb : WVb;
    const int i = (blockIdx.x * 256 + threadIdx.x) * 4;
    float4 f = *(const float4*)(src + i);
    ushortx4 o;
    o[0] = f2bf(f.x); o[1] = f2bf(f.y); o[2] = f2bf(f.z); o[3] = f2bf(f.w);
    *(ushortx4*)(dst + i) = o;
}

// ---------- K0b: WO [kk=n*64+h][d] fp32 -> WOt [d][kk] bf16 ----------
__global__ __launch_bounds__(256) void wo_transpose_kernel(
    const float* __restrict__ WO, unsigned short* __restrict__ WOt)
{
    __shared__ float t[64][65];
    const int kk0 = blockIdx.x * 64, d0 = blockIdx.y * 64;
    #pragma unroll
    for (int it = 0; it < 16; ++it) {
        int idx = it * 256 + threadIdx.x;
        int r = idx >> 6, c = idx & 63;
        t[r][c] = WO[(kk0 + r) * DD_ + d0 + c];
    }
    __syncthreads();
    #pragma unroll
    for (int it = 0; it < 16; ++it) {
        int idx = it * 256 + threadIdx.x;
        int r = idx >> 6, c = idx & 63;
        WOt[(d0 + r) * DD_ + kk0 + c] = f2bf(t[c][r]);
    }
}

// ---------- K1: QKV projections, m97 GEMM with swizzled LDS ----------
__global__ __launch_bounds__(256) void qkv_m97_kernel(
    const unsigned short* __restrict__ residB,
    const unsigned short* __restrict__ WQb,
    const unsigned short* __restrict__ WKb,
    const unsigned short* __restrict__ WVb,
    unsigned short* __restrict__ q, unsigned short* __restrict__ kk,
    unsigned short* __restrict__ vT)
{
    __shared__ unsigned short As[128 * 64];
    __shared__ unsigned short Bs[128 * 64];
    const int tid = threadIdx.x;
    const int l = tid & 63, w = tid >> 6;
    const int quad = l >> 4, lan = l & 15;
    const int z = blockIdx.z;
    const unsigned short* W = (z == 0) ? WQb : (z == 1) ? WKb : WVb;
    unsigned short* dst = (z == 0) ? q : (z == 1) ? kk : vT;
    const int mBase = blockIdx.x * 128;
    const int nBase = blockIdx.y * 128;
    const int wm = (w & 1) * 64, wn = (w >> 1) * 64;

    floatx4 acc[4][4];
    #pragma unroll
    for (int a = 0; a < 4; ++a)
        #pragma unroll
        for (int b = 0; b < 4; ++b)
            #pragma unroll
            for (int i = 0; i < 4; ++i) acc[a][b][i] = 0.f;

    const int sr = l >> 3;
    const int sgx = ((l & 7) ^ sr) * 8;

    for (int k0 = 0; k0 < DD_; k0 += 64) {
        __syncthreads();
        #pragma unroll
        for (int i = 0; i < 4; ++i) {
            const int row = i * 32 + w * 8 + sr;
            gl_lds16(residB + (size_t)(mBase + row) * DD_ + k0 + sgx,
                     As + i * 2048 + w * 512);
            gl_lds16(W + (size_t)(nBase + row) * DD_ + k0 + sgx,
                     Bs + i * 2048 + w * 512);
        }
        __syncthreads();
        #pragma unroll
        for (int ks = 0; ks < 2; ++ks) {
            const int fo = (((ks * 4 + quad) ^ (lan & 7)) << 3);
            bf16x8 a[4], b[4];
            #pragma unroll
            for (int mi = 0; mi < 4; ++mi)
                a[mi] = *(const bf16x8*)(As + (wm + mi * 16 + lan) * 64 + fo);
            #pragma unroll
            for (int ni = 0; ni < 4; ++ni)
                b[ni] = *(const bf16x8*)(Bs + (wn + ni * 16 + lan) * 64 + fo);
            #pragma unroll
            for (int mi = 0; mi < 4; ++mi)
                #pragma unroll
                for (int ni = 0; ni < 4; ++ni)
                    acc[mi][ni] = __builtin_amdgcn_mfma_f32_16x16x32_bf16(
                        a[mi], b[ni], acc[mi][ni], 0, 0, 0);
        }
    }
    const int headU = (nBase + wn) >> 6;
    const float scale = (z == 0) ? 0.125f * 1.44269504088896340736f : 1.0f;
    if (z < 2) {
        #pragma unroll
        for (int mi = 0; mi < 4; ++mi)
            #pragma unroll
            for (int ni = 0; ni < 4; ++ni)
                #pragma unroll
                for (int reg = 0; reg < 4; ++reg) {
                    int m = mBase + wm + mi * 16 + quad * 4 + reg;
                    int bb = m >> 11, ss = m & 2047;
                    int h = ni * 16 + lan;
                    dst[((size_t)(bb * NH_ + headU) * SS_ + ss) * 64 + h] =
                        f2bf(acc[mi][ni][reg] * scale);
                }
    } else {
        #pragma unroll
        for (int mi = 0; mi < 4; ++mi) {
            const int m0 = mBase + wm + mi * 16 + quad * 4;
            const int bb = m0 >> 11, ss0 = m0 & 2047;
            #pragma unroll
            for (int ni = 0; ni < 4; ++ni) {
                const int h = ni * 16 + lan;
                bf16x4 ob;
                #pragma unroll
                for (int reg = 0; reg < 4; ++reg)
                    ob[reg] = static_cast<__bf16>(acc[mi][ni][reg]);
                *(bf16x4*)(dst + ((size_t)(bb * NH_ + headU) * 64 + h) * SS_ + ss0) = ob;
            }
        }
    }
}

// ---------- K2: flash attention, counted-vmcnt deep pipeline ----------
__global__ __launch_bounds__(512, 4) void flash_mfma_kernel(
    const unsigned short* __restrict__ q,
    const unsigned short* __restrict__ k,
    const unsigned short* __restrict__ vT,
    unsigned short* __restrict__ attn)
{
    __shared__ unsigned short ldsK[3][64 * 64];   // staged 3 ahead
    __shared__ unsigned short ldsV[3][64 * 64];   // staged 2 ahead
    const int l = threadIdx.x & 63, w = threadIdx.x >> 6;   // w: 0..7
    const int quad = l >> 4, lan = l & 15;
    const int f = blockIdx.x;                               // 0..511
    const int bn = (f & 7) | (((f >> 3) & 3) << 3);         // XCD swizzle
    const int g = f >> 5;                                   // 0..15
    const int c = (g < 8) ? (15 - g) : (g - 8);             // balanced pairing
    const int nit = 2 * c + 2;                              // k-tiles, >= 2

    const unsigned short* Qg = q  + (size_t)bn * SS_ * 64;
    const unsigned short* Kg = k  + (size_t)bn * SS_ * 64;
    const unsigned short* Vg = vT + (size_t)bn * 64 * SS_;

    const int srl = l >> 3;
    const int sgx = (l & 7) ^ srl;

    const int qAbs = c * 128 + w * 16 + lan;

    const unsigned short* Qr = Qg + (size_t)qAbs * 64 + quad * 8;
    bf16x8 Qf0 = *(const bf16x8*)(Qr);
    bf16x8 Qf1 = *(const bf16x8*)(Qr + 32);

    bf16x4 ones;
    #pragma unroll
    for (int i = 0; i < 4; ++i) ones[i] = static_cast<__bf16>(1.0f);

    float mrow = -INFINITY;
    floatx4 l_acc;                       // only [0] kept consistent
    floatx4 o[4];
    #pragma unroll
    for (int i = 0; i < 4; ++i) l_acc[i] = 0.f;
    #pragma unroll
    for (int t = 0; t < 4; ++t)
        #pragma unroll
        for (int i = 0; i < 4; ++i) o[t][i] = 0.f;

    // each wave stages 8 rows (one gl_lds16) per tile
    #define STAGE_K(kt_, buf_)                                                  \
        gl_lds16(Kg + (size_t)((kt_) * 64 + w * 8 + srl) * 64 + sgx * 8,        \
                 &ldsK[buf_][w * 8 * 64]);
    #define STAGE_V(kt_, buf_)                                                  \
        gl_lds16(Vg + (size_t)(w * 8 + srl) * SS_ + (kt_) * 64 + sgx * 8,       \
                 &ldsV[buf_][w * 8 * 64]);
    #define QK_TILE(dst_, buf_)                                                 \
        { const unsigned short* Kb_ = &ldsK[buf_][0];                           \
          _Pragma("unroll")                                                     \
          for (int nt = 0; nt < 4; ++nt) {                                      \
              const unsigned short* kr_ = Kb_ + (nt * 16 + lan) * 64;           \
              bf16x8 K0_ = *(const bf16x8*)(kr_ + ((quad ^ (lan & 7)) << 3));   \
              bf16x8 K1_ = *(const bf16x8*)(kr_ + (((quad + 4) ^ (lan & 7)) << 3)); \
              floatx4 zz_; zz_[0] = zz_[1] = zz_[2] = zz_[3] = 0.f;             \
              dst_[nt] = __builtin_amdgcn_mfma_f32_16x16x32_bf16(K0_, Qf0, zz_, 0, 0, 0); \
              dst_[nt] = __builtin_amdgcn_mfma_f32_16x16x32_bf16(K1_, Qf1, dst_[nt], 0, 0, 0); } }

    // prologue: K(0),V(0),K(1) drained+barrier; then K(2),V(1) in flight.
    STAGE_K(0, 0);
    STAGE_V(0, 0);
    STAGE_K(1, 1);
    asm volatile("s_waitcnt vmcnt(0) lgkmcnt(0)" ::: "memory");
    __builtin_amdgcn_s_barrier();
    asm volatile("" ::: "memory");
    { const int t2 = (2 < nit) ? 2 : nit - 1; STAGE_K(t2, 2); }
    STAGE_V(1, 1);
    floatx4 scCur[4], scNext[4];
    QK_TILE(scCur, 0);

    for (int kt = 0; kt < nit; ++kt) {
        const int kBase = kt * 64;
        // counted barrier: own loads older than last iter's 2 are drained;
        // last iter's 2 (K(kt+2),V(kt+1)) stay in flight across the barrier.
        asm volatile("s_waitcnt vmcnt(2) lgkmcnt(0)" ::: "memory");
        __builtin_amdgcn_s_barrier();
        asm volatile("" ::: "memory");
        { const int tk = (kt + 3 < nit) ? kt + 3 : nit - 1;
          STAGE_K(tk, (kt + 3) % 3); }
        { const int tv = (kt + 2 < nit) ? kt + 2 : nit - 1;
          STAGE_V(tv, (kt + 2) % 3); }
        if (kt + 1 < nit) {
            QK_TILE(scNext, (kt + 1) % 3);   // K(kt+1): staged kt-2, drained at this barrier
        }
        if (kt >= nit - 2) {   // last two tiles intersect the 128-row diagonal
            #pragma unroll
            for (int nt = 0; nt < 4; ++nt)
                #pragma unroll
                for (int reg = 0; reg < 4; ++reg)
                    if (kBase + nt * 16 + quad * 4 + reg > qAbs)
                        scCur[nt][reg] = -INFINITY;
        }
        // softmax on scCur (QK issued one iter ago -> MFMA long done)
        float mx = scCur[0][0];
        #pragma unroll
        for (int nt = 0; nt < 4; ++nt)
            #pragma unroll
            for (int reg = 0; reg < 4; ++reg) mx = fmaxf(mx, scCur[nt][reg]);
        mx = fmaxf(mx, __shfl_xor(mx, 16, 64));
        mx = fmaxf(mx, __shfl_xor(mx, 32, 64));
        const float mnew = fmaxf(mrow, mx);
        if (!__all(mx <= mrow)) {        // uniform skip: max unchanged on all lanes
            const float alpha = exp2f(mrow - mnew);
            l_acc[0] *= alpha;
            #pragma unroll
            for (int t = 0; t < 4; ++t)
                #pragma unroll
                for (int i = 0; i < 4; ++i) o[t][i] *= alpha;
        }
        mrow = mnew;
        bf16x4 pb[4];
        #pragma unroll
        for (int nt = 0; nt < 4; ++nt)
            #pragma unroll
            for (int reg = 0; reg < 4; ++reg)
                pb[nt][reg] = static_cast<__bf16>(exp2f(scCur[nt][reg] - mnew));
        // l += sum_k P (ones-column MFMAs)
        #pragma unroll
        for (int nt = 0; nt < 4; ++nt)
            l_acc = mfma_pv(ones, pb[nt], l_acc);
        // O^T += V^T . P^T   (V(kt): staged kt-2, drained at this barrier)
        const unsigned short* Vb = &ldsV[kt % 3][0];
        #pragma unroll
        for (int t = 0; t < 4; ++t) {
            const unsigned short* vr = Vb + (t * 16 + lan) * 64 + ((quad & 1) << 2);
            #pragma unroll
            for (int nt = 0; nt < 4; ++nt) {
                const int g2 = nt * 2 + (quad >> 1);
                bf16x4 Vf = *(const bf16x4*)(vr + ((g2 ^ (lan & 7)) << 3));
                o[t] = mfma_pv(Vf, pb[nt], o[t]);
            }
        }
        if (kt + 1 < nit) {
            #pragma unroll
            for (int nt = 0; nt < 4; ++nt) scCur[nt] = scNext[nt];
        }
    }
    // drain tail stages: no LDS-DMA may be in flight at s_endpgm (workgroup
    // teardown reassigns LDS -> late-landing DMA corrupts/faults). R11 bug.
    asm volatile("s_waitcnt vmcnt(0)" ::: "memory");
    const float rl = 1.f / l_acc[0];
    #pragma unroll
    for (int t = 0; t < 4; ++t) {
        bf16x4 ob;
        #pragma unroll
        for (int reg = 0; reg < 4; ++reg)
            ob[reg] = static_cast<__bf16>(o[t][reg] * rl);
        *(bf16x4*)(attn + ((size_t)bn * SS_ + qAbs) * 64 + t * 16 + quad * 4) = ob;
    }
    #undef STAGE_K
    #undef STAGE_V
    #undef QK_TILE
}

// ---------- K3: output projection, m97 GEMM with swizzled LDS ----------
__global__ __launch_bounds__(256) void out_m97_kernel(
    const unsigned short* __restrict__ attn,
    const unsigned short* __restrict__ WOt,
    float* __restrict__ out)
{
    __shared__ unsigned short As[128 * 64];
    __shared__ unsigned short Bs[128 * 64];
    const int tid = threadIdx.x;
    const int l = tid & 63, w = tid >> 6;
    const int quad = l >> 4, lan = l & 15;
    const int mBase = blockIdx.x * 128;
    const int nBase = blockIdx.y * 128;
    const int wm = (w & 1) * 64, wn = (w >> 1) * 64;
    const int bbU = mBase >> 11;
    const int ssBase = mBase & 2047;

    floatx4 acc[4][4];
    #pragma unroll
    for (int a = 0; a < 4; ++a)
        #pragma unroll
        for (int b = 0; b < 4; ++b)
            #pragma unroll
            for (int i = 0; i < 4; ++i) acc[a][b][i] = 0.f;

    const int sr = l >> 3;
    const int sgx = ((l & 7) ^ sr) * 8;

    for (int kt = 0; kt < 16; ++kt) {
        const int k0 = kt * 64;
        __syncthreads();
        #pragma unroll
        for (int i = 0; i < 4; ++i) {
            const int row = i * 32 + w * 8 + sr;
            gl_lds16(attn + ((size_t)(bbU * NH_ + kt) * SS_ + ssBase + row) * 64 + sgx,
                     As + i * 2048 + w * 512);
            gl_lds16(WOt + (size_t)(nBase + row) * DD_ + k0 + sgx,
                     Bs + i * 2048 + w * 512);
        }
        __syncthreads();
        #pragma unroll
        for (int ks = 0; ks < 2; ++ks) {
            const int fo = (((ks * 4 + quad) ^ (lan & 7)) << 3);
            bf16x8 a[4], b[4];
            #pragma unroll
            for (int mi = 0; mi < 4; ++mi)
                a[mi] = *(const bf16x8*)(As + (wm + mi * 16 + lan) * 64 + fo);
            #pragma unroll
            for (int ni = 0; ni < 4; ++ni)
                b[ni] = *(const bf16x8*)(Bs + (wn + ni * 16 + lan) * 64 + fo);
            #pragma unroll
            for (int mi = 0; mi < 4; ++mi)
                #pragma unroll
                for (int ni = 0; ni < 4; ++ni)
                    acc[mi][ni] = __builtin_amdgcn_mfma_f32_16x16x32_bf16(
                        a[mi], b[ni], acc[mi][ni], 0, 0, 0);
        }
    }
    #pragma unroll
    for (int mi = 0; mi < 4; ++mi)
        #pragma unroll
        for (int ni = 0; ni < 4; ++ni)
            #pragma unroll
            for (int reg = 0; reg < 4; ++reg) {
                int m = mBase + wm + mi * 16 + quad * 4 + reg;
                out[(size_t)m * DD_ + nBase + wn + ni * 16 + lan] = acc[mi][ni][reg];
            }
}

extern "C" void kernel_launch(void* const* d_in, const int* in_sizes, int n_in,
                              void* d_out, int out_size, void* d_ws, size_t ws_size,
                              hipStream_t stream) {
    const float* resid = (const float*)d_in[0];
    const float* WQ    = (const float*)d_in[1];
    const float* WK    = (const float*)d_in[2];
    const float* WV    = (const float*)d_in[3];
    const float* WO    = (const float*)d_in[4];
    float* out = (float*)d_out;

    unsigned short* q      = (unsigned short*)d_ws;
    unsigned short* kk     = q      + 4194304;
    unsigned short* vT     = kk     + 4194304;
    unsigned short* attn   = vT     + 4194304;
    unsigned short* residB = attn   + 4194304;
    unsigned short* WQb    = residB + 4194304;
    unsigned short* WKb    = WQb    + 1048576;
    unsigned short* WVb    = WKb    + 1048576;
    unsigned short* WOt    = WVb    + 1048576;

    cast_bf16_kernel<<<dim3(4096, 4), 256, 0, stream>>>(
        resid, WQ, WK, WV, residB, WQb, WKb, WVb);
    wo_transpose_kernel<<<dim3(16, 16), 256, 0, stream>>>(WO, WOt);
    qkv_m97_kernel<<<dim3(32, 8, 3), 256, 0, stream>>>(
        residB, WQb, WKb, WVb, q, kk, vT);
    flash_mfma_kernel<<<dim3(512), dim3(512), 0, stream>>>(q, kk, vT, attn);
    out_m97_kernel<<<dim3(32, 8), 256, 0, stream>>>(attn, WOt, out);
}

// Round 3
// 196.016 us; speedup vs baseline: 1.0406x; 1.0406x over previous
//
#include <hip/hip_runtime.h>
#include <math.h>

// R13: revert to R10 skeleton (1024x256 blocks, 4 blocks/CU, guarded
// prefetch, __syncthreads) + BATCHED LDS reads in flash.
// Post-mortem R12: counted-vmcnt pipeline regressed (62us vs 53): fewer
// independent blocks/CU + convoy'd 8-wave barriers. Real bottleneck theory:
// VGPR=56 starved the scheduler -> ds_read->mfma chains serialized at
// ~120cy/read (~24 reads/iter ~= 2900cy/iter latency). Fix: spend VGPRs
// (launch_bounds allows 128): hoist K-frag reads (K0v/K1v[4]) before QK
// MFMAs, hoist all 16 V b64 reads BEFORE softmax so softmax VALU covers
// their latency. All indices compile-time-constant (rule #20).
// GEMMs (m97 + xor-swizzled LDS, R8-verified) unchanged.
// Layouts (verified R2-R9, absmax 7.8e-3):
//   x32 A-frag: m=lane&15, k=(lane>>4)*8+j ; B-frag: n=lane&15, k=(lane>>4)*8+j
//   x16 A/B-frag: idx=lane&15, k=(lane>>4)*4+j
//   C/D (all 16x16): col=lane&15, row=(lane>>4)*4+reg

#define SS_ 2048
#define DD_ 1024
#define NH_ 16
#define BN_ 32
#define BS_ 4096

typedef __bf16 bf16x8 __attribute__((ext_vector_type(8)));
typedef __bf16 bf16x4 __attribute__((ext_vector_type(4)));
typedef short shortx4 __attribute__((ext_vector_type(4)));
typedef float floatx4 __attribute__((ext_vector_type(4)));
typedef unsigned short ushortx4 __attribute__((ext_vector_type(4)));

__device__ __forceinline__ unsigned short f2bf(float f) {
    union { float f; unsigned u; } v; v.f = f;
    unsigned r = v.u + 0x7FFFu + ((v.u >> 16) & 1u);   // RNE
    return (unsigned short)(r >> 16);
}

__device__ __forceinline__ floatx4 mfma_pv(bf16x4 a, bf16x4 b, floatx4 c) {
#if __has_builtin(__builtin_amdgcn_mfma_f32_16x16x16_bf16)
    return __builtin_amdgcn_mfma_f32_16x16x16_bf16(a, b, c, 0, 0, 0);
#else
    return __builtin_amdgcn_mfma_f32_16x16x16bf16_1k(
        __builtin_bit_cast(shortx4, a), __builtin_bit_cast(shortx4, b), c, 0, 0, 0);
#endif
}

__device__ __forceinline__ void gl_lds16(const unsigned short* g, unsigned short* l) {
    __builtin_amdgcn_global_load_lds(
        (const __attribute__((address_space(1))) unsigned int*)g,
        (__attribute__((address_space(3))) unsigned int*)l, 16, 0, 0);
}

// ---------- K0a: cast resid + WQ/WK/WV to bf16 ----------
__global__ __launch_bounds__(256) void cast_bf16_kernel(
    const float* __restrict__ resid, const float* __restrict__ WQ,
    const float* __restrict__ WK, const float* __restrict__ WV,
    unsigned short* __restrict__ residB, unsigned short* __restrict__ WQb,
    unsigned short* __restrict__ WKb, unsigned short* __restrict__ WVb)
{
    const int z = blockIdx.y;
    if (z > 0 && blockIdx.x >= 1024) return;
    const float* src = (z == 0) ? resid : (z == 1) ? WQ : (z == 2) ? WK : WV;
    unsigned short* dst = (z == 0) ? residB : (z == 1) ? WQb : (z == 2) ? WKb : WVb;
    const int i = (blockIdx.x * 256 + threadIdx.x) * 4;
    float4 f = *(const float4*)(src + i);
    ushortx4 o;
    o[0] = f2bf(f.x); o[1] = f2bf(f.y); o[2] = f2bf(f.z); o[3] = f2bf(f.w);
    *(ushortx4*)(dst + i) = o;
}

// ---------- K0b: WO [kk=n*64+h][d] fp32 -> WOt [d][kk] bf16 ----------
__global__ __launch_bounds__(256) void wo_transpose_kernel(
    const float* __restrict__ WO, unsigned short* __restrict__ WOt)
{
    __shared__ float t[64][65];
    const int kk0 = blockIdx.x * 64, d0 = blockIdx.y * 64;
    #pragma unroll
    for (int it = 0; it < 16; ++it) {
        int idx = it * 256 + threadIdx.x;
        int r = idx >> 6, c = idx & 63;
        t[r][c] = WO[(kk0 + r) * DD_ + d0 + c];
    }
    __syncthreads();
    #pragma unroll
    for (int it = 0; it < 16; ++it) {
        int idx = it * 256 + threadIdx.x;
        int r = idx >> 6, c = idx & 63;
        WOt[(d0 + r) * DD_ + kk0 + c] = f2bf(t[c][r]);
    }
}

// ---------- K1: QKV projections, m97 GEMM with swizzled LDS ----------
__global__ __launch_bounds__(256) void qkv_m97_kernel(
    const unsigned short* __restrict__ residB,
    const unsigned short* __restrict__ WQb,
    const unsigned short* __restrict__ WKb,
    const unsigned short* __restrict__ WVb,
    unsigned short* __restrict__ q, unsigned short* __restrict__ kk,
    unsigned short* __restrict__ vT)
{
    __shared__ unsigned short As[128 * 64];
    __shared__ unsigned short Bs[128 * 64];
    const int tid = threadIdx.x;
    const int l = tid & 63, w = tid >> 6;
    const int quad = l >> 4, lan = l & 15;
    const int z = blockIdx.z;
    const unsigned short* W = (z == 0) ? WQb : (z == 1) ? WKb : WVb;
    unsigned short* dst = (z == 0) ? q : (z == 1) ? kk : vT;
    const int mBase = blockIdx.x * 128;
    const int nBase = blockIdx.y * 128;
    const int wm = (w & 1) * 64, wn = (w >> 1) * 64;

    floatx4 acc[4][4];
    #pragma unroll
    for (int a = 0; a < 4; ++a)
        #pragma unroll
        for (int b = 0; b < 4; ++b)
            #pragma unroll
            for (int i = 0; i < 4; ++i) acc[a][b][i] = 0.f;

    const int sr = l >> 3;
    const int sgx = ((l & 7) ^ sr) * 8;

    for (int k0 = 0; k0 < DD_; k0 += 64) {
        __syncthreads();
        #pragma unroll
        for (int i = 0; i < 4; ++i) {
            const int row = i * 32 + w * 8 + sr;
            gl_lds16(residB + (size_t)(mBase + row) * DD_ + k0 + sgx,
                     As + i * 2048 + w * 512);
            gl_lds16(W + (size_t)(nBase + row) * DD_ + k0 + sgx,
                     Bs + i * 2048 + w * 512);
        }
        __syncthreads();
        #pragma unroll
        for (int ks = 0; ks < 2; ++ks) {
            const int fo = (((ks * 4 + quad) ^ (lan & 7)) << 3);
            bf16x8 a[4], b[4];
            #pragma unroll
            for (int mi = 0; mi < 4; ++mi)
                a[mi] = *(const bf16x8*)(As + (wm + mi * 16 + lan) * 64 + fo);
            #pragma unroll
            for (int ni = 0; ni < 4; ++ni)
                b[ni] = *(const bf16x8*)(Bs + (wn + ni * 16 + lan) * 64 + fo);
            #pragma unroll
            for (int mi = 0; mi < 4; ++mi)
                #pragma unroll
                for (int ni = 0; ni < 4; ++ni)
                    acc[mi][ni] = __builtin_amdgcn_mfma_f32_16x16x32_bf16(
                        a[mi], b[ni], acc[mi][ni], 0, 0, 0);
        }
    }
    const int headU = (nBase + wn) >> 6;
    const float scale = (z == 0) ? 0.125f * 1.44269504088896340736f : 1.0f;
    if (z < 2) {
        #pragma unroll
        for (int mi = 0; mi < 4; ++mi)
            #pragma unroll
            for (int ni = 0; ni < 4; ++ni)
                #pragma unroll
                for (int reg = 0; reg < 4; ++reg) {
                    int m = mBase + wm + mi * 16 + quad * 4 + reg;
                    int bb = m >> 11, ss = m & 2047;
                    int h = ni * 16 + lan;
                    dst[((size_t)(bb * NH_ + headU) * SS_ + ss) * 64 + h] =
                        f2bf(acc[mi][ni][reg] * scale);
                }
    } else {
        #pragma unroll
        for (int mi = 0; mi < 4; ++mi) {
            const int m0 = mBase + wm + mi * 16 + quad * 4;
            const int bb = m0 >> 11, ss0 = m0 & 2047;
            #pragma unroll
            for (int ni = 0; ni < 4; ++ni) {
                const int h = ni * 16 + lan;
                bf16x4 ob;
                #pragma unroll
                for (int reg = 0; reg < 4; ++reg)
                    ob[reg] = static_cast<__bf16>(acc[mi][ni][reg]);
                *(bf16x4*)(dst + ((size_t)(bb * NH_ + headU) * 64 + h) * SS_ + ss0) = ob;
            }
        }
    }
}

// ---------- K2: flash attention, batched LDS reads ----------
__global__ __launch_bounds__(256, 4) void flash_mfma_kernel(
    const unsigned short* __restrict__ q,
    const unsigned short* __restrict__ k,
    const unsigned short* __restrict__ vT,
    unsigned short* __restrict__ attn)
{
    __shared__ unsigned short ldsK[3][64 * 64];   // triple: QK runs one ahead
    __shared__ unsigned short ldsV[2][64 * 64];
    const int l = threadIdx.x & 63, w = threadIdx.x >> 6;   // w: 0..3
    const int quad = l >> 4, lan = l & 15;
    const int f = blockIdx.x;                               // 0..1023
    const int bn = (f & 7) | (((f >> 3) & 3) << 3);         // XCD swizzle
    const int chunk = 31 - (f >> 5);                        // heavy blocks first

    const unsigned short* Qg = q  + (size_t)bn * SS_ * 64;
    const unsigned short* Kg = k  + (size_t)bn * SS_ * 64;
    const unsigned short* Vg = vT + (size_t)bn * 64 * SS_;

    const int srl = l >> 3;
    const int sgx = (l & 7) ^ srl;

    const int qRow0 = chunk * 64 + w * 16;
    const int qAbs = qRow0 + lan;

    const unsigned short* Qr = Qg + (size_t)qAbs * 64 + quad * 8;
    bf16x8 Qf0 = *(const bf16x8*)(Qr);
    bf16x8 Qf1 = *(const bf16x8*)(Qr + 32);

    bf16x4 ones;
    #pragma unroll
    for (int i = 0; i < 4; ++i) ones[i] = static_cast<__bf16>(1.0f);

    float mrow = -INFINITY;
    floatx4 l_acc;                       // only [0] kept consistent
    floatx4 o[4];
    #pragma unroll
    for (int i = 0; i < 4; ++i) l_acc[i] = 0.f;
    #pragma unroll
    for (int t = 0; t < 4; ++t)
        #pragma unroll
        for (int i = 0; i < 4; ++i) o[t][i] = 0.f;

    // staging helpers: each wave stages 16 rows (2x gl_lds16) per tile
    #define STAGE_K(kt_, buf_)                                                  \
        { const int row0_ = w * 16, kB_ = (kt_) * 64;                           \
          gl_lds16(Kg + (size_t)(kB_ + row0_ + srl) * 64 + sgx * 8,             \
                   &ldsK[buf_][row0_ * 64]);                                    \
          gl_lds16(Kg + (size_t)(kB_ + row0_ + 8 + srl) * 64 + sgx * 8,         \
                   &ldsK[buf_][(row0_ + 8) * 64]); }
    #define STAGE_V(kt_, buf_)                                                  \
        { const int row0_ = w * 16, kB_ = (kt_) * 64;                           \
          gl_lds16(Vg + (size_t)(row0_ + srl) * SS_ + kB_ + sgx * 8,            \
                   &ldsV[buf_][row0_ * 64]);                                    \
          gl_lds16(Vg + (size_t)(row0_ + 8 + srl) * SS_ + kB_ + sgx * 8,        \
                   &ldsV[buf_][(row0_ + 8) * 64]); }
    // batched: issue all 8 ds_read_b128 first, then 8 MFMAs (breaks the
    // read->mfma serial chain; 32 transient VGPRs)
    #define QK_TILE(dst_, buf_)                                                 \
        { const unsigned short* Kb_ = &ldsK[buf_][0];                           \
          bf16x8 K0v_[4], K1v_[4];                                              \
          _Pragma("unroll")                                                     \
          for (int nt = 0; nt < 4; ++nt) {                                      \
              const unsigned short* kr_ = Kb_ + (nt * 16 + lan) * 64;           \
              K0v_[nt] = *(const bf16x8*)(kr_ + ((quad ^ (lan & 7)) << 3));     \
              K1v_[nt] = *(const bf16x8*)(kr_ + (((quad + 4) ^ (lan & 7)) << 3)); } \
          _Pragma("unroll")                                                     \
          for (int nt = 0; nt < 4; ++nt) {                                      \
              floatx4 zz_; zz_[0] = zz_[1] = zz_[2] = zz_[3] = 0.f;             \
              dst_[nt] = __builtin_amdgcn_mfma_f32_16x16x32_bf16(K0v_[nt], Qf0, zz_, 0, 0, 0); \
              dst_[nt] = __builtin_amdgcn_mfma_f32_16x16x32_bf16(K1v_[nt], Qf1, dst_[nt], 0, 0, 0); } }

    // prologue: stage(0); barrier; stage K(1); scCur = QK(0)
    STAGE_K(0, 0);
    STAGE_V(0, 0);
    __syncthreads();
    if (chunk >= 1) STAGE_K(1, 1);
    floatx4 scCur[4], scNext[4];
    QK_TILE(scCur, 0);

    for (int kt = 0; kt <= chunk; ++kt) {
        const int kBase = kt * 64;
        __syncthreads();   // stage(kt+1) visible; prior readers drained
        if (kt + 2 <= chunk) STAGE_K(kt + 2, (kt + 2) % 3);
        if (kt + 1 <= chunk) {
            STAGE_V(kt + 1, (kt + 1) & 1);
            QK_TILE(scNext, (kt + 1) % 3);   // issue next QK before softmax
        }
        // batched V reads for THIS tile: issue all 16 ds_read_b64 now so
        // their latency hides under the softmax VALU work below
        const unsigned short* Vb = &ldsV[kt & 1][0];
        bf16x4 Vfv[4][4];
        #pragma unroll
        for (int t = 0; t < 4; ++t) {
            const unsigned short* vr = Vb + (t * 16 + lan) * 64 + ((quad & 1) << 2);
            #pragma unroll
            for (int nt = 0; nt < 4; ++nt) {
                const int g2 = nt * 2 + (quad >> 1);
                Vfv[t][nt] = *(const bf16x4*)(vr + ((g2 ^ (lan & 7)) << 3));
            }
        }
        if (kt == chunk) {   // diagonal: mask k > q
            #pragma unroll
            for (int nt = 0; nt < 4; ++nt)
                #pragma unroll
                for (int reg = 0; reg < 4; ++reg)
                    if (kBase + nt * 16 + quad * 4 + reg > qAbs)
                        scCur[nt][reg] = -INFINITY;
        }
        // softmax on scCur (computed one iter ago -> MFMA long done)
        float mx = scCur[0][0];
        #pragma unroll
        for (int nt = 0; nt < 4; ++nt)
            #pragma unroll
            for (int reg = 0; reg < 4; ++reg) mx = fmaxf(mx, scCur[nt][reg]);
        mx = fmaxf(mx, __shfl_xor(mx, 16, 64));
        mx = fmaxf(mx, __shfl_xor(mx, 32, 64));
        const float mnew = fmaxf(mrow, mx);
        if (!__all(mx <= mrow)) {        // uniform skip: max unchanged on all lanes
            const float alpha = exp2f(mrow - mnew);
            l_acc[0] *= alpha;
            #pragma unroll
            for (int t = 0; t < 4; ++t)
                #pragma unroll
                for (int i = 0; i < 4; ++i) o[t][i] *= alpha;
        }
        mrow = mnew;
        bf16x4 pb[4];
        #pragma unroll
        for (int nt = 0; nt < 4; ++nt)
            #pragma unroll
            for (int reg = 0; reg < 4; ++reg)
                pb[nt][reg] = static_cast<__bf16>(exp2f(scCur[nt][reg] - mnew));
        // l += sum_k P (ones-column MFMAs)
        #pragma unroll
        for (int nt = 0; nt < 4; ++nt)
            l_acc = mfma_pv(ones, pb[nt], l_acc);
        // O^T += V^T . P^T  (V frags already in registers)
        #pragma unroll
        for (int t = 0; t < 4; ++t)
            #pragma unroll
            for (int nt = 0; nt < 4; ++nt)
                o[t] = mfma_pv(Vfv[t][nt], pb[nt], o[t]);
        #pragma unroll
        for (int nt = 0; nt < 4; ++nt) scCur[nt] = scNext[nt];
    }
    const float rl = 1.f / l_acc[0];
    #pragma unroll
    for (int t = 0; t < 4; ++t) {
        bf16x4 ob;
        #pragma unroll
        for (int reg = 0; reg < 4; ++reg)
            ob[reg] = static_cast<__bf16>(o[t][reg] * rl);
        *(bf16x4*)(attn + ((size_t)bn * SS_ + qAbs) * 64 + t * 16 + quad * 4) = ob;
    }
    #undef STAGE_K
    #undef STAGE_V
    #undef QK_TILE
}

// ---------- K3: output projection, m97 GEMM with swizzled LDS ----------
__global__ __launch_bounds__(256) void out_m97_kernel(
    const unsigned short* __restrict__ attn,
    const unsigned short* __restrict__ WOt,
    float* __restrict__ out)
{
    __shared__ unsigned short As[128 * 64];
    __shared__ unsigned short Bs[128 * 64];
    const int tid = threadIdx.x;
    const int l = tid & 63, w = tid >> 6;
    const int quad = l >> 4, lan = l & 15;
    const int mBase = blockIdx.x * 128;
    const int nBase = blockIdx.y * 128;
    const int wm = (w & 1) * 64, wn = (w >> 1) * 64;
    const int bbU = mBase >> 11;
    const int ssBase = mBase & 2047;

    floatx4 acc[4][4];
    #pragma unroll
    for (int a = 0; a < 4; ++a)
        #pragma unroll
        for (int b = 0; b < 4; ++b)
            #pragma unroll
            for (int i = 0; i < 4; ++i) acc[a][b][i] = 0.f;

    const int sr = l >> 3;
    const int sgx = ((l & 7) ^ sr) * 8;

    for (int kt = 0; kt < 16; ++kt) {
        const int k0 = kt * 64;
        __syncthreads();
        #pragma unroll
        for (int i = 0; i < 4; ++i) {
            const int row = i * 32 + w * 8 + sr;
            gl_lds16(attn + ((size_t)(bbU * NH_ + kt) * SS_ + ssBase + row) * 64 + sgx,
                     As + i * 2048 + w * 512);
            gl_lds16(WOt + (size_t)(nBase + row) * DD_ + k0 + sgx,
                     Bs + i * 2048 + w * 512);
        }
        __syncthreads();
        #pragma unroll
        for (int ks = 0; ks < 2; ++ks) {
            const int fo = (((ks * 4 + quad) ^ (lan & 7)) << 3);
            bf16x8 a[4], b[4];
            #pragma unroll
            for (int mi = 0; mi < 4; ++mi)
                a[mi] = *(const bf16x8*)(As + (wm + mi * 16 + lan) * 64 + fo);
            #pragma unroll
            for (int ni = 0; ni < 4; ++ni)
                b[ni] = *(const bf16x8*)(Bs + (wn + ni * 16 + lan) * 64 + fo);
            #pragma unroll
            for (int mi = 0; mi < 4; ++mi)
                #pragma unroll
                for (int ni = 0; ni < 4; ++ni)
                    acc[mi][ni] = __builtin_amdgcn_mfma_f32_16x16x32_bf16(
                        a[mi], b[ni], acc[mi][ni], 0, 0, 0);
        }
    }
    #pragma unroll
    for (int mi = 0; mi < 4; ++mi)
        #pragma unroll
        for (int ni = 0; ni < 4; ++ni)
            #pragma unroll
            for (int reg = 0; reg < 4; ++reg) {
                int m = mBase + wm + mi * 16 + quad * 4 + reg;
                out[(size_t)m * DD_ + nBase + wn + ni * 16 + lan] = acc[mi][ni][reg];
            }
}

extern "C" void kernel_launch(void* const* d_in, const int* in_sizes, int n_in,
                              void* d_out, int out_size, void* d_ws, size_t ws_size,
                              hipStream_t stream) {
    const float* resid = (const float*)d_in[0];
    const float* WQ    = (const float*)d_in[1];
    const float* WK    = (const float*)d_in[2];
    const float* WV    = (const float*)d_in[3];
    const float* WO    = (const float*)d_in[4];
    float* out = (float*)d_out;

    unsigned short* q      = (unsigned short*)d_ws;
    unsigned short* kk     = q      + 4194304;
    unsigned short* vT     = kk     + 4194304;
    unsigned short* attn   = vT     + 4194304;
    unsigned short* residB = attn   + 4194304;
    unsigned short* WQb    = residB + 4194304;
    unsigned short* WKb    = WQb    + 1048576;
    unsigned short* WVb    = WKb    + 1048576;
    unsigned short* WOt    = WVb    + 1048576;

    cast_bf16_kernel<<<dim3(4096, 4), 256, 0, stream>>>(
        resid, WQ, WK, WV, residB, WQb, WKb, WVb);
    wo_transpose_kernel<<<dim3(16, 16), 256, 0, stream>>>(WO, WOt);
    qkv_m97_kernel<<<dim3(32, 8, 3), 256, 0, stream>>>(
        residB, WQb, WKb, WVb, q, kk, vT);
    flash_mfma_kernel<<<dim3(1024), dim3(256), 0, stream>>>(q, kk, vT, attn);
    out_m97_kernel<<<dim3(32, 8), 256, 0, stream>>>(attn, WOt, out);
}

// Round 6
// 195.415 us; speedup vs baseline: 1.0438x; 1.0031x over previous
//
#include <hip/hip_runtime.h>
#include <math.h>

// R15 (resubmit; R5 attempt hit GPUAcquisitionTimeout — never ran):
// (1) flash = R13 body (last-known-good, 54.2us) + balanced per-CU
// chunk mapping: CU group a gets chunks {31-a, a+16, 15-a, a}, sum 62 for
// every a (was 76-4a -> 80..52 imbalance, occupancy-decay tail at 28%).
// (2) qkv: q now stored TRANSPOSED [bn][h][s] via the vectorized bf16x4
// epilogue (scale folded); kills 64-scalar-2B-store epilogue for q
// (~16.7M scalar stores across q+k was ~27us of store issue). K keeps
// [s][h] (gl_lds16 staging needs contiguous h). flash Q-load becomes 16
// strided scalar loads once per block (negligible).
// R14 post-mortem: V-direct-from-global tripped the replay-determinism
// check (unexplained race) -> reverted; DMA-fill-ceiling theory refuted
// (m97 sustains 21.7 B/cyc/CU vs flash's 8.1).
// Layouts (verified R2-R13, absmax 7.8e-3):
//   x32 A-frag: m=lane&15, k=(lane>>4)*8+j ; B-frag: n=lane&15, k=(lane>>4)*8+j
//   x16 A/B-frag: idx=lane&15, k=(lane>>4)*4+j
//   C/D (all 16x16): col=lane&15, row=(lane>>4)*4+reg

#define SS_ 2048
#define DD_ 1024
#define NH_ 16
#define BN_ 32
#define BS_ 4096

typedef __bf16 bf16x8 __attribute__((ext_vector_type(8)));
typedef __bf16 bf16x4 __attribute__((ext_vector_type(4)));
typedef short shortx4 __attribute__((ext_vector_type(4)));
typedef float floatx4 __attribute__((ext_vector_type(4)));
typedef unsigned short ushortx4 __attribute__((ext_vector_type(4)));

__device__ __forceinline__ unsigned short f2bf(float f) {
    union { float f; unsigned u; } v; v.f = f;
    unsigned r = v.u + 0x7FFFu + ((v.u >> 16) & 1u);   // RNE
    return (unsigned short)(r >> 16);
}

__device__ __forceinline__ floatx4 mfma_pv(bf16x4 a, bf16x4 b, floatx4 c) {
#if __has_builtin(__builtin_amdgcn_mfma_f32_16x16x16_bf16)
    return __builtin_amdgcn_mfma_f32_16x16x16_bf16(a, b, c, 0, 0, 0);
#else
    return __builtin_amdgcn_mfma_f32_16x16x16bf16_1k(
        __builtin_bit_cast(shortx4, a), __builtin_bit_cast(shortx4, b), c, 0, 0, 0);
#endif
}

__device__ __forceinline__ void gl_lds16(const unsigned short* g, unsigned short* l) {
    __builtin_amdgcn_global_load_lds(
        (const __attribute__((address_space(1))) unsigned int*)g,
        (__attribute__((address_space(3))) unsigned int*)l, 16, 0, 0);
}

// ---------- K0a: cast resid + WQ/WK/WV to bf16 ----------
__global__ __launch_bounds__(256) void cast_bf16_kernel(
    const float* __restrict__ resid, const float* __restrict__ WQ,
    const float* __restrict__ WK, const float* __restrict__ WV,
    unsigned short* __restrict__ residB, unsigned short* __restrict__ WQb,
    unsigned short* __restrict__ WKb, unsigned short* __restrict__ WVb)
{
    const int z = blockIdx.y;
    if (z > 0 && blockIdx.x >= 1024) return;
    const float* src = (z == 0) ? resid : (z == 1) ? WQ : (z == 2) ? WK : WV;
    unsigned short* dst = (z == 0) ? residB : (z == 1) ? WQb : (z == 2) ? WKb : WVb;
    const int i = (blockIdx.x * 256 + threadIdx.x) * 4;
    float4 f = *(const float4*)(src + i);
    ushortx4 o;
    o[0] = f2bf(f.x); o[1] = f2bf(f.y); o[2] = f2bf(f.z); o[3] = f2bf(f.w);
    *(ushortx4*)(dst + i) = o;
}

// ---------- K0b: WO [kk=n*64+h][d] fp32 -> WOt [d][kk] bf16 ----------
__global__ __launch_bounds__(256) void wo_transpose_kernel(
    const float* __restrict__ WO, unsigned short* __restrict__ WOt)
{
    __shared__ float t[64][65];
    const int kk0 = blockIdx.x * 64, d0 = blockIdx.y * 64;
    #pragma unroll
    for (int it = 0; it < 16; ++it) {
        int idx = it * 256 + threadIdx.x;
        int r = idx >> 6, c = idx & 63;
        t[r][c] = WO[(kk0 + r) * DD_ + d0 + c];
    }
    __syncthreads();
    #pragma unroll
    for (int it = 0; it < 16; ++it) {
        int idx = it * 256 + threadIdx.x;
        int r = idx >> 6, c = idx & 63;
        WOt[(d0 + r) * DD_ + kk0 + c] = f2bf(t[c][r]);
    }
}

// ---------- K1: QKV projections, m97 GEMM with swizzled LDS ----------
// q (z=0): stored TRANSPOSED [bn][h][s] with scale folded (vector epilogue)
// kk (z=1): [bn][s][h] scalar epilogue (staging requires contiguous h)
// vT (z=2): [bn][h][s] vector epilogue
__global__ __launch_bounds__(256) void qkv_m97_kernel(
    const unsigned short* __restrict__ residB,
    const unsigned short* __restrict__ WQb,
    const unsigned short* __restrict__ WKb,
    const unsigned short* __restrict__ WVb,
    unsigned short* __restrict__ q, unsigned short* __restrict__ kk,
    unsigned short* __restrict__ vT)
{
    __shared__ unsigned short As[128 * 64];
    __shared__ unsigned short Bs[128 * 64];
    const int tid = threadIdx.x;
    const int l = tid & 63, w = tid >> 6;
    const int quad = l >> 4, lan = l & 15;
    const int z = blockIdx.z;
    const unsigned short* W = (z == 0) ? WQb : (z == 1) ? WKb : WVb;
    unsigned short* dst = (z == 0) ? q : (z == 1) ? kk : vT;
    const int mBase = blockIdx.x * 128;
    const int nBase = blockIdx.y * 128;
    const int wm = (w & 1) * 64, wn = (w >> 1) * 64;

    floatx4 acc[4][4];
    #pragma unroll
    for (int a = 0; a < 4; ++a)
        #pragma unroll
        for (int b = 0; b < 4; ++b)
            #pragma unroll
            for (int i = 0; i < 4; ++i) acc[a][b][i] = 0.f;

    const int sr = l >> 3;
    const int sgx = ((l & 7) ^ sr) * 8;

    for (int k0 = 0; k0 < DD_; k0 += 64) {
        __syncthreads();
        #pragma unroll
        for (int i = 0; i < 4; ++i) {
            const int row = i * 32 + w * 8 + sr;
            gl_lds16(residB + (size_t)(mBase + row) * DD_ + k0 + sgx,
                     As + i * 2048 + w * 512);
            gl_lds16(W + (size_t)(nBase + row) * DD_ + k0 + sgx,
                     Bs + i * 2048 + w * 512);
        }
        __syncthreads();
        #pragma unroll
        for (int ks = 0; ks < 2; ++ks) {
            const int fo = (((ks * 4 + quad) ^ (lan & 7)) << 3);
            bf16x8 a[4], b[4];
            #pragma unroll
            for (int mi = 0; mi < 4; ++mi)
                a[mi] = *(const bf16x8*)(As + (wm + mi * 16 + lan) * 64 + fo);
            #pragma unroll
            for (int ni = 0; ni < 4; ++ni)
                b[ni] = *(const bf16x8*)(Bs + (wn + ni * 16 + lan) * 64 + fo);
            #pragma unroll
            for (int mi = 0; mi < 4; ++mi)
                #pragma unroll
                for (int ni = 0; ni < 4; ++ni)
                    acc[mi][ni] = __builtin_amdgcn_mfma_f32_16x16x32_bf16(
                        a[mi], b[ni], acc[mi][ni], 0, 0, 0);
        }
    }
    const int headU = (nBase + wn) >> 6;
    if (z == 1) {
        // K: [bn][s][h], scalar stores (16-lane 32B segments)
        #pragma unroll
        for (int mi = 0; mi < 4; ++mi)
            #pragma unroll
            for (int ni = 0; ni < 4; ++ni)
                #pragma unroll
                for (int reg = 0; reg < 4; ++reg) {
                    int m = mBase + wm + mi * 16 + quad * 4 + reg;
                    int bb = m >> 11, ss = m & 2047;
                    int h = ni * 16 + lan;
                    dst[((size_t)(bb * NH_ + headU) * SS_ + ss) * 64 + h] =
                        f2bf(acc[mi][ni][reg]);
                }
    } else {
        // Q (scaled) and V: [bn][h][s], vectorized bf16x4 stores along s
        const float scl = (z == 0) ? 0.125f * 1.44269504088896340736f : 1.0f;
        #pragma unroll
        for (int mi = 0; mi < 4; ++mi) {
            const int m0 = mBase + wm + mi * 16 + quad * 4;
            const int bb = m0 >> 11, ss0 = m0 & 2047;
            #pragma unroll
            for (int ni = 0; ni < 4; ++ni) {
                const int h = ni * 16 + lan;
                bf16x4 ob;
                #pragma unroll
                for (int reg = 0; reg < 4; ++reg)
                    ob[reg] = static_cast<__bf16>(acc[mi][ni][reg] * scl);
                *(bf16x4*)(dst + ((size_t)(bb * NH_ + headU) * 64 + h) * SS_ + ss0) = ob;
            }
        }
    }
}

// ---------- K2: flash attention (R13 body + balanced chunks, Q^T load) ----------
__global__ __launch_bounds__(256, 4) void flash_mfma_kernel(
    const unsigned short* __restrict__ q,
    const unsigned short* __restrict__ k,
    const unsigned short* __restrict__ vT,
    unsigned short* __restrict__ attn)
{
    __shared__ unsigned short ldsK[3][64 * 64];   // triple: QK runs one ahead
    __shared__ unsigned short ldsV[2][64 * 64];
    const int l = threadIdx.x & 63, w = threadIdx.x >> 6;   // w: 0..3
    const int quad = l >> 4, lan = l & 15;
    const int f = blockIdx.x;                               // 0..1023
    const int bn = (f & 7) | (((f >> 3) & 3) << 3);         // XCD swizzle
    const int g = f >> 5;                                   // 0..31
    // balanced, bijective chunk mapping: CU group a gets {31-a, a+16, 15-a, a}
    // -> per-CU sum 62 for every a; heavy first.
    const int ch = (g < 8) ? (31 - g)
                 : (g < 16) ? (g + 8)
                 : (g < 24) ? (15 - (g - 16))
                 : (g - 24);

    const unsigned short* Qg = q  + (size_t)bn * 64 * SS_;  // [h][s] now
    const unsigned short* Kg = k  + (size_t)bn * SS_ * 64;  // [s][h]
    const unsigned short* Vg = vT + (size_t)bn * 64 * SS_;  // [h][s]

    const int srl = l >> 3;
    const int sgx = (l & 7) ^ srl;

    const int qRow0 = ch * 64 + w * 16;
    const int qAbs = qRow0 + lan;

    // Q from [h][s]: 16 strided scalar loads, once per block (cheap)
    bf16x8 Qf0, Qf1;
    #pragma unroll
    for (int j = 0; j < 8; ++j) {
        Qf0[j] = *(const __bf16*)(Qg + (size_t)(quad * 8 + j) * SS_ + qAbs);
        Qf1[j] = *(const __bf16*)(Qg + (size_t)(quad * 8 + j + 32) * SS_ + qAbs);
    }

    bf16x4 ones;
    #pragma unroll
    for (int i = 0; i < 4; ++i) ones[i] = static_cast<__bf16>(1.0f);

    float mrow = -INFINITY;
    floatx4 l_acc;                       // only [0] kept consistent
    floatx4 o[4];
    #pragma unroll
    for (int i = 0; i < 4; ++i) l_acc[i] = 0.f;
    #pragma unroll
    for (int t = 0; t < 4; ++t)
        #pragma unroll
        for (int i = 0; i < 4; ++i) o[t][i] = 0.f;

    // staging helpers: each wave stages 16 rows (2x gl_lds16) per tile
    #define STAGE_K(kt_, buf_)                                                  \
        { const int row0_ = w * 16, kB_ = (kt_) * 64;                           \
          gl_lds16(Kg + (size_t)(kB_ + row0_ + srl) * 64 + sgx * 8,             \
                   &ldsK[buf_][row0_ * 64]);                                    \
          gl_lds16(Kg + (size_t)(kB_ + row0_ + 8 + srl) * 64 + sgx * 8,         \
                   &ldsK[buf_][(row0_ + 8) * 64]); }
    #define STAGE_V(kt_, buf_)                                                  \
        { const int row0_ = w * 16, kB_ = (kt_) * 64;                           \
          gl_lds16(Vg + (size_t)(row0_ + srl) * SS_ + kB_ + sgx * 8,            \
                   &ldsV[buf_][row0_ * 64]);                                    \
          gl_lds16(Vg + (size_t)(row0_ + 8 + srl) * SS_ + kB_ + sgx * 8,        \
                   &ldsV[buf_][(row0_ + 8) * 64]); }
    // batched: issue all 8 ds_read_b128 first, then 8 MFMAs
    #define QK_TILE(dst_, buf_)                                                 \
        { const unsigned short* Kb_ = &ldsK[buf_][0];                           \
          bf16x8 K0v_[4], K1v_[4];                                              \
          _Pragma("unroll")                                                     \
          for (int nt = 0; nt < 4; ++nt) {                                      \
              const unsigned short* kr_ = Kb_ + (nt * 16 + lan) * 64;           \
              K0v_[nt] = *(const bf16x8*)(kr_ + ((quad ^ (lan & 7)) << 3));     \
              K1v_[nt] = *(const bf16x8*)(kr_ + (((quad + 4) ^ (lan & 7)) << 3)); } \
          _Pragma("unroll")                                                     \
          for (int nt = 0; nt < 4; ++nt) {                                      \
              floatx4 zz_; zz_[0] = zz_[1] = zz_[2] = zz_[3] = 0.f;             \
              dst_[nt] = __builtin_amdgcn_mfma_f32_16x16x32_bf16(K0v_[nt], Qf0, zz_, 0, 0, 0); \
              dst_[nt] = __builtin_amdgcn_mfma_f32_16x16x32_bf16(K1v_[nt], Qf1, dst_[nt], 0, 0, 0); } }

    // prologue: stage(0); barrier; stage K(1); scCur = QK(0)
    STAGE_K(0, 0);
    STAGE_V(0, 0);
    __syncthreads();
    if (ch >= 1) STAGE_K(1, 1);
    floatx4 scCur[4], scNext[4];
    QK_TILE(scCur, 0);

    for (int kt = 0; kt <= ch; ++kt) {
        const int kBase = kt * 64;
        __syncthreads();   // stage(kt+1) visible; prior readers drained
        if (kt + 2 <= ch) STAGE_K(kt + 2, (kt + 2) % 3);
        if (kt + 1 <= ch) {
            STAGE_V(kt + 1, (kt + 1) & 1);
            QK_TILE(scNext, (kt + 1) % 3);   // issue next QK before softmax
        }
        // batched V reads for THIS tile: latency hides under softmax VALU
        const unsigned short* Vb = &ldsV[kt & 1][0];
        bf16x4 Vfv[4][4];
        #pragma unroll
        for (int t = 0; t < 4; ++t) {
            const unsigned short* vr = Vb + (t * 16 + lan) * 64 + ((quad & 1) << 2);
            #pragma unroll
            for (int nt = 0; nt < 4; ++nt) {
                const int g2 = nt * 2 + (quad >> 1);
                Vfv[t][nt] = *(const bf16x4*)(vr + ((g2 ^ (lan & 7)) << 3));
            }
        }
        if (kt == ch) {   // diagonal: mask k > q
            #pragma unroll
            for (int nt = 0; nt < 4; ++nt)
                #pragma unroll
                for (int reg = 0; reg < 4; ++reg)
                    if (kBase + nt * 16 + quad * 4 + reg > qAbs)
                        scCur[nt][reg] = -INFINITY;
        }
        // softmax on scCur (computed one iter ago -> MFMA long done)
        float mx = scCur[0][0];
        #pragma unroll
        for (int nt = 0; nt < 4; ++nt)
            #pragma unroll
            for (int reg = 0; reg < 4; ++reg) mx = fmaxf(mx, scCur[nt][reg]);
        mx = fmaxf(mx, __shfl_xor(mx, 16, 64));
        mx = fmaxf(mx, __shfl_xor(mx, 32, 64));
        const float mnew = fmaxf(mrow, mx);
        if (!__all(mx <= mrow)) {        // uniform skip: max unchanged on all lanes
            const float alpha = exp2f(mrow - mnew);
            l_acc[0] *= alpha;
            #pragma unroll
            for (int t = 0; t < 4; ++t)
                #pragma unroll
                for (int i = 0; i < 4; ++i) o[t][i] *= alpha;
        }
        mrow = mnew;
        bf16x4 pb[4];
        #pragma unroll
        for (int nt = 0; nt < 4; ++nt)
            #pragma unroll
            for (int reg = 0; reg < 4; ++reg)
                pb[nt][reg] = static_cast<__bf16>(exp2f(scCur[nt][reg] - mnew));
        // l += sum_k P (ones-column MFMAs)
        #pragma unroll
        for (int nt = 0; nt < 4; ++nt)
            l_acc = mfma_pv(ones, pb[nt], l_acc);
        // O^T += V^T . P^T  (V frags already in registers)
        #pragma unroll
        for (int t = 0; t < 4; ++t)
            #pragma unroll
            for (int nt = 0; nt < 4; ++nt)
                o[t] = mfma_pv(Vfv[t][nt], pb[nt], o[t]);
        #pragma unroll
        for (int nt = 0; nt < 4; ++nt) scCur[nt] = scNext[nt];
    }
    const float rl = 1.f / l_acc[0];
    #pragma unroll
    for (int t = 0; t < 4; ++t) {
        bf16x4 ob;
        #pragma unroll
        for (int reg = 0; reg < 4; ++reg)
            ob[reg] = static_cast<__bf16>(o[t][reg] * rl);
        *(bf16x4*)(attn + ((size_t)bn * SS_ + qAbs) * 64 + t * 16 + quad * 4) = ob;
    }
    #undef STAGE_K
    #undef STAGE_V
    #undef QK_TILE
}

// ---------- K3: output projection, m97 GEMM with swizzled LDS ----------
__global__ __launch_bounds__(256) void out_m97_kernel(
    const unsigned short* __restrict__ attn,
    const unsigned short* __restrict__ WOt,
    float* __restrict__ out)
{
    __shared__ unsigned short As[128 * 64];
    __shared__ unsigned short Bs[128 * 64];
    const int tid = threadIdx.x;
    const int l = tid & 63, w = tid >> 6;
    const int quad = l >> 4, lan = l & 15;
    const int mBase = blockIdx.x * 128;
    const int nBase = blockIdx.y * 128;
    const int wm = (w & 1) * 64, wn = (w >> 1) * 64;
    const int bbU = mBase >> 11;
    const int ssBase = mBase & 2047;

    floatx4 acc[4][4];
    #pragma unroll
    for (int a = 0; a < 4; ++a)
        #pragma unroll
        for (int b = 0; b < 4; ++b)
            #pragma unroll
            for (int i = 0; i < 4; ++i) acc[a][b][i] = 0.f;

    const int sr = l >> 3;
    const int sgx = ((l & 7) ^ sr) * 8;

    for (int kt = 0; kt < 16; ++kt) {
        const int k0 = kt * 64;
        __syncthreads();
        #pragma unroll
        for (int i = 0; i < 4; ++i) {
            const int row = i * 32 + w * 8 + sr;
            gl_lds16(attn + ((size_t)(bbU * NH_ + kt) * SS_ + ssBase + row) * 64 + sgx,
                     As + i * 2048 + w * 512);
            gl_lds16(WOt + (size_t)(nBase + row) * DD_ + k0 + sgx,
                     Bs + i * 2048 + w * 512);
        }
        __syncthreads();
        #pragma unroll
        for (int ks = 0; ks < 2; ++ks) {
            const int fo = (((ks * 4 + quad) ^ (lan & 7)) << 3);
            bf16x8 a[4], b[4];
            #pragma unroll
            for (int mi = 0; mi < 4; ++mi)
                a[mi] = *(const bf16x8*)(As + (wm + mi * 16 + lan) * 64 + fo);
            #pragma unroll
            for (int ni = 0; ni < 4; ++ni)
                b[ni] = *(const bf16x8*)(Bs + (wn + ni * 16 + lan) * 64 + fo);
            #pragma unroll
            for (int mi = 0; mi < 4; ++mi)
                #pragma unroll
                for (int ni = 0; ni < 4; ++ni)
                    acc[mi][ni] = __builtin_amdgcn_mfma_f32_16x16x32_bf16(
                        a[mi], b[ni], acc[mi][ni], 0, 0, 0);
        }
    }
    #pragma unroll
    for (int mi = 0; mi < 4; ++mi)
        #pragma unroll
        for (int ni = 0; ni < 4; ++ni)
            #pragma unroll
            for (int reg = 0; reg < 4; ++reg) {
                int m = mBase + wm + mi * 16 + quad * 4 + reg;
                out[(size_t)m * DD_ + nBase + wn + ni * 16 + lan] = acc[mi][ni][reg];
            }
}

extern "C" void kernel_launch(void* const* d_in, const int* in_sizes, int n_in,
                              void* d_out, int out_size, void* d_ws, size_t ws_size,
                              hipStream_t stream) {
    const float* resid = (const float*)d_in[0];
    const float* WQ    = (const float*)d_in[1];
    const float* WK    = (const float*)d_in[2];
    const float* WV    = (const float*)d_in[3];
    const float* WO    = (const float*)d_in[4];
    float* out = (float*)d_out;

    unsigned short* q      = (unsigned short*)d_ws;
    unsigned short* kk     = q      + 4194304;
    unsigned short* vT     = kk     + 4194304;
    unsigned short* attn   = vT     + 4194304;
    unsigned short* residB = attn   + 4194304;
    unsigned short* WQb    = residB + 4194304;
    unsigned short* WKb    = WQb    + 1048576;
    unsigned short* WVb    = WKb    + 1048576;
    unsigned short* WOt    = WVb    + 1048576;

    cast_bf16_kernel<<<dim3(4096, 4), 256, 0, stream>>>(
        resid, WQ, WK, WV, residB, WQb, WKb, WVb);
    wo_transpose_kernel<<<dim3(16, 16), 256, 0, stream>>>(WO, WOt);
    qkv_m97_kernel<<<dim3(32, 8, 3), 256, 0, stream>>>(
        residB, WQb, WKb, WVb, q, kk, vT);
    flash_mfma_kernel<<<dim3(1024), dim3(256), 0, stream>>>(q, kk, vT, attn);
    out_m97_kernel<<<dim3(32, 8), 256, 0, stream>>>(attn, WOt, out);
}

// Round 7
// 180.598 us; speedup vs baseline: 1.1294x; 1.0820x over previous
//
#include <hip/hip_runtime.h>
#include <math.h>

// R16: attack the 143us of non-flash time. Theory: qkv (3 blk/CU) and out
// (1 blk/CU!) run the m97 2-barrier loop latency-EXPOSED (m102: square-1024
// = 90 TF, same regime): each of 16 K-iters eats the full stage->drain->
// barrier latency with no co-resident block to overlap. Fix via TLP:
// BM=64 tiles (LDS 24KB) -> qkv grid (64,8,3)=1536 blk = 6/CU, out grid
// (64,8)=512 blk = 2/CU. MFMA order per output unchanged -> bitwise-same
// results. cast: 1D grid drops ~9K empty-block dispatches.
// flash: R15 body untouched (52.4us known-good; 4 scheduling theories
// falsified -- R11/R12 counted-vmcnt, R13 batched-reads, R15 balance).
// Layouts (verified R2-R15, absmax 7.8e-3):
//   x32 A-frag: m=lane&15, k=(lane>>4)*8+j ; B-frag: n=lane&15, k=(lane>>4)*8+j
//   x16 A/B-frag: idx=lane&15, k=(lane>>4)*4+j
//   C/D (all 16x16): col=lane&15, row=(lane>>4)*4+reg

#define SS_ 2048
#define DD_ 1024
#define NH_ 16
#define BN_ 32
#define BS_ 4096

typedef __bf16 bf16x8 __attribute__((ext_vector_type(8)));
typedef __bf16 bf16x4 __attribute__((ext_vector_type(4)));
typedef short shortx4 __attribute__((ext_vector_type(4)));
typedef float floatx4 __attribute__((ext_vector_type(4)));
typedef unsigned short ushortx4 __attribute__((ext_vector_type(4)));

__device__ __forceinline__ unsigned short f2bf(float f) {
    union { float f; unsigned u; } v; v.f = f;
    unsigned r = v.u + 0x7FFFu + ((v.u >> 16) & 1u);   // RNE
    return (unsigned short)(r >> 16);
}

__device__ __forceinline__ floatx4 mfma_pv(bf16x4 a, bf16x4 b, floatx4 c) {
#if __has_builtin(__builtin_amdgcn_mfma_f32_16x16x16_bf16)
    return __builtin_amdgcn_mfma_f32_16x16x16_bf16(a, b, c, 0, 0, 0);
#else
    return __builtin_amdgcn_mfma_f32_16x16x16bf16_1k(
        __builtin_bit_cast(shortx4, a), __builtin_bit_cast(shortx4, b), c, 0, 0, 0);
#endif
}

__device__ __forceinline__ void gl_lds16(const unsigned short* g, unsigned short* l) {
    __builtin_amdgcn_global_load_lds(
        (const __attribute__((address_space(1))) unsigned int*)g,
        (__attribute__((address_space(3))) unsigned int*)l, 16, 0, 0);
}

// ---------- K0a: cast resid + WQ/WK/WV to bf16 (1D grid, no empty blocks) ----------
__global__ __launch_bounds__(256) void cast_bf16_kernel(
    const float* __restrict__ resid, const float* __restrict__ WQ,
    const float* __restrict__ WK, const float* __restrict__ WV,
    unsigned short* __restrict__ residB, unsigned short* __restrict__ WQb,
    unsigned short* __restrict__ WKb, unsigned short* __restrict__ WVb)
{
    const int x = blockIdx.x;
    int z, ix;
    if (x < 4096) { z = 0; ix = x; }
    else { z = 1 + ((x - 4096) >> 10); ix = (x - 4096) & 1023; }
    const float* src = (z == 0) ? resid : (z == 1) ? WQ : (z == 2) ? WK : WV;
    unsigned short* dst = (z == 0) ? residB : (z == 1) ? WQb : (z == 2) ? WKb : WVb;
    const int i = (ix * 256 + threadIdx.x) * 4;
    float4 f = *(const float4*)(src + i);
    ushortx4 o;
    o[0] = f2bf(f.x); o[1] = f2bf(f.y); o[2] = f2bf(f.z); o[3] = f2bf(f.w);
    *(ushortx4*)(dst + i) = o;
}

// ---------- K0b: WO [kk=n*64+h][d] fp32 -> WOt [d][kk] bf16 ----------
__global__ __launch_bounds__(256) void wo_transpose_kernel(
    const float* __restrict__ WO, unsigned short* __restrict__ WOt)
{
    __shared__ float t[64][65];
    const int kk0 = blockIdx.x * 64, d0 = blockIdx.y * 64;
    #pragma unroll
    for (int it = 0; it < 16; ++it) {
        int idx = it * 256 + threadIdx.x;
        int r = idx >> 6, c = idx & 63;
        t[r][c] = WO[(kk0 + r) * DD_ + d0 + c];
    }
    __syncthreads();
    #pragma unroll
    for (int it = 0; it < 16; ++it) {
        int idx = it * 256 + threadIdx.x;
        int r = idx >> 6, c = idx & 63;
        WOt[(d0 + r) * DD_ + kk0 + c] = f2bf(t[c][r]);
    }
}

// ---------- K1: QKV projections, m97 GEMM, BM=64 tile (6 blk/CU) ----------
// q (z=0): TRANSPOSED [bn][h][s] with scale folded (vector epilogue)
// kk (z=1): [bn][s][h] scalar epilogue (staging requires contiguous h)
// vT (z=2): [bn][h][s] vector epilogue
__global__ __launch_bounds__(256) void qkv_m97_kernel(
    const unsigned short* __restrict__ residB,
    const unsigned short* __restrict__ WQb,
    const unsigned short* __restrict__ WKb,
    const unsigned short* __restrict__ WVb,
    unsigned short* __restrict__ q, unsigned short* __restrict__ kk,
    unsigned short* __restrict__ vT)
{
    __shared__ unsigned short As[64 * 64];
    __shared__ unsigned short Bs[128 * 64];
    const int tid = threadIdx.x;
    const int l = tid & 63, w = tid >> 6;
    const int quad = l >> 4, lan = l & 15;
    const int z = blockIdx.z;
    const unsigned short* W = (z == 0) ? WQb : (z == 1) ? WKb : WVb;
    unsigned short* dst = (z == 0) ? q : (z == 1) ? kk : vT;
    const int mBase = blockIdx.x * 64;
    const int nBase = blockIdx.y * 128;
    const int wm = (w & 1) * 32, wn = (w >> 1) * 64;

    floatx4 acc[2][4];
    #pragma unroll
    for (int a = 0; a < 2; ++a)
        #pragma unroll
        for (int b = 0; b < 4; ++b)
            #pragma unroll
            for (int i = 0; i < 4; ++i) acc[a][b][i] = 0.f;

    const int sr = l >> 3;
    const int sgx = ((l & 7) ^ sr) * 8;

    for (int k0 = 0; k0 < DD_; k0 += 64) {
        __syncthreads();
        #pragma unroll
        for (int i = 0; i < 2; ++i) {
            const int row = i * 32 + w * 8 + sr;
            gl_lds16(residB + (size_t)(mBase + row) * DD_ + k0 + sgx,
                     As + i * 2048 + w * 512);
        }
        #pragma unroll
        for (int i = 0; i < 4; ++i) {
            const int row = i * 32 + w * 8 + sr;
            gl_lds16(W + (size_t)(nBase + row) * DD_ + k0 + sgx,
                     Bs + i * 2048 + w * 512);
        }
        __syncthreads();
        #pragma unroll
        for (int ks = 0; ks < 2; ++ks) {
            const int fo = (((ks * 4 + quad) ^ (lan & 7)) << 3);
            bf16x8 a[2], b[4];
            #pragma unroll
            for (int mi = 0; mi < 2; ++mi)
                a[mi] = *(const bf16x8*)(As + (wm + mi * 16 + lan) * 64 + fo);
            #pragma unroll
            for (int ni = 0; ni < 4; ++ni)
                b[ni] = *(const bf16x8*)(Bs + (wn + ni * 16 + lan) * 64 + fo);
            #pragma unroll
            for (int mi = 0; mi < 2; ++mi)
                #pragma unroll
                for (int ni = 0; ni < 4; ++ni)
                    acc[mi][ni] = __builtin_amdgcn_mfma_f32_16x16x32_bf16(
                        a[mi], b[ni], acc[mi][ni], 0, 0, 0);
        }
    }
    const int headU = (nBase + wn) >> 6;
    if (z == 1) {
        // K: [bn][s][h], scalar stores (16-lane 32B segments)
        #pragma unroll
        for (int mi = 0; mi < 2; ++mi)
            #pragma unroll
            for (int ni = 0; ni < 4; ++ni)
                #pragma unroll
                for (int reg = 0; reg < 4; ++reg) {
                    int m = mBase + wm + mi * 16 + quad * 4 + reg;
                    int bb = m >> 11, ss = m & 2047;
                    int h = ni * 16 + lan;
                    dst[((size_t)(bb * NH_ + headU) * SS_ + ss) * 64 + h] =
                        f2bf(acc[mi][ni][reg]);
                }
    } else {
        // Q (scaled) and V: [bn][h][s], vectorized bf16x4 stores along s
        const float scl = (z == 0) ? 0.125f * 1.44269504088896340736f : 1.0f;
        #pragma unroll
        for (int mi = 0; mi < 2; ++mi) {
            const int m0 = mBase + wm + mi * 16 + quad * 4;
            const int bb = m0 >> 11, ss0 = m0 & 2047;
            #pragma unroll
            for (int ni = 0; ni < 4; ++ni) {
                const int h = ni * 16 + lan;
                bf16x4 ob;
                #pragma unroll
                for (int reg = 0; reg < 4; ++reg)
                    ob[reg] = static_cast<__bf16>(acc[mi][ni][reg] * scl);
                *(bf16x4*)(dst + ((size_t)(bb * NH_ + headU) * 64 + h) * SS_ + ss0) = ob;
            }
        }
    }
}

// ---------- K2: flash attention (R15 body, untouched) ----------
__global__ __launch_bounds__(256, 4) void flash_mfma_kernel(
    const unsigned short* __restrict__ q,
    const unsigned short* __restrict__ k,
    const unsigned short* __restrict__ vT,
    unsigned short* __restrict__ attn)
{
    __shared__ unsigned short ldsK[3][64 * 64];   // triple: QK runs one ahead
    __shared__ unsigned short ldsV[2][64 * 64];
    const int l = threadIdx.x & 63, w = threadIdx.x >> 6;   // w: 0..3
    const int quad = l >> 4, lan = l & 15;
    const int f = blockIdx.x;                               // 0..1023
    const int bn = (f & 7) | (((f >> 3) & 3) << 3);         // XCD swizzle
    const int g = f >> 5;                                   // 0..31
    const int ch = (g < 8) ? (31 - g)
                 : (g < 16) ? (g + 8)
                 : (g < 24) ? (15 - (g - 16))
                 : (g - 24);

    const unsigned short* Qg = q  + (size_t)bn * 64 * SS_;  // [h][s]
    const unsigned short* Kg = k  + (size_t)bn * SS_ * 64;  // [s][h]
    const unsigned short* Vg = vT + (size_t)bn * 64 * SS_;  // [h][s]

    const int srl = l >> 3;
    const int sgx = (l & 7) ^ srl;

    const int qRow0 = ch * 64 + w * 16;
    const int qAbs = qRow0 + lan;

    // Q from [h][s]: 16 strided scalar loads, once per block (cheap)
    bf16x8 Qf0, Qf1;
    #pragma unroll
    for (int j = 0; j < 8; ++j) {
        Qf0[j] = *(const __bf16*)(Qg + (size_t)(quad * 8 + j) * SS_ + qAbs);
        Qf1[j] = *(const __bf16*)(Qg + (size_t)(quad * 8 + j + 32) * SS_ + qAbs);
    }

    bf16x4 ones;
    #pragma unroll
    for (int i = 0; i < 4; ++i) ones[i] = static_cast<__bf16>(1.0f);

    float mrow = -INFINITY;
    floatx4 l_acc;                       // only [0] kept consistent
    floatx4 o[4];
    #pragma unroll
    for (int i = 0; i < 4; ++i) l_acc[i] = 0.f;
    #pragma unroll
    for (int t = 0; t < 4; ++t)
        #pragma unroll
        for (int i = 0; i < 4; ++i) o[t][i] = 0.f;

    #define STAGE_K(kt_, buf_)                                                  \
        { const int row0_ = w * 16, kB_ = (kt_) * 64;                           \
          gl_lds16(Kg + (size_t)(kB_ + row0_ + srl) * 64 + sgx * 8,             \
                   &ldsK[buf_][row0_ * 64]);                                    \
          gl_lds16(Kg + (size_t)(kB_ + row0_ + 8 + srl) * 64 + sgx * 8,         \
                   &ldsK[buf_][(row0_ + 8) * 64]); }
    #define STAGE_V(kt_, buf_)                                                  \
        { const int row0_ = w * 16, kB_ = (kt_) * 64;                           \
          gl_lds16(Vg + (size_t)(row0_ + srl) * SS_ + kB_ + sgx * 8,            \
                   &ldsV[buf_][row0_ * 64]);                                    \
          gl_lds16(Vg + (size_t)(row0_ + 8 + srl) * SS_ + kB_ + sgx * 8,        \
                   &ldsV[buf_][(row0_ + 8) * 64]); }
    #define QK_TILE(dst_, buf_)                                                 \
        { const unsigned short* Kb_ = &ldsK[buf_][0];                           \
          bf16x8 K0v_[4], K1v_[4];                                              \
          _Pragma("unroll")                                                     \
          for (int nt = 0; nt < 4; ++nt) {                                      \
              const unsigned short* kr_ = Kb_ + (nt * 16 + lan) * 64;           \
              K0v_[nt] = *(const bf16x8*)(kr_ + ((quad ^ (lan & 7)) << 3));     \
              K1v_[nt] = *(const bf16x8*)(kr_ + (((quad + 4) ^ (lan & 7)) << 3)); } \
          _Pragma("unroll")                                                     \
          for (int nt = 0; nt < 4; ++nt) {                                      \
              floatx4 zz_; zz_[0] = zz_[1] = zz_[2] = zz_[3] = 0.f;             \
              dst_[nt] = __builtin_amdgcn_mfma_f32_16x16x32_bf16(K0v_[nt], Qf0, zz_, 0, 0, 0); \
              dst_[nt] = __builtin_amdgcn_mfma_f32_16x16x32_bf16(K1v_[nt], Qf1, dst_[nt], 0, 0, 0); } }

    // prologue: stage(0); barrier; stage K(1); scCur = QK(0)
    STAGE_K(0, 0);
    STAGE_V(0, 0);
    __syncthreads();
    if (ch >= 1) STAGE_K(1, 1);
    floatx4 scCur[4], scNext[4];
    QK_TILE(scCur, 0);

    for (int kt = 0; kt <= ch; ++kt) {
        const int kBase = kt * 64;
        __syncthreads();   // stage(kt+1) visible; prior readers drained
        if (kt + 2 <= ch) STAGE_K(kt + 2, (kt + 2) % 3);
        if (kt + 1 <= ch) {
            STAGE_V(kt + 1, (kt + 1) & 1);
            QK_TILE(scNext, (kt + 1) % 3);   // issue next QK before softmax
        }
        // batched V reads for THIS tile: latency hides under softmax VALU
        const unsigned short* Vb = &ldsV[kt & 1][0];
        bf16x4 Vfv[4][4];
        #pragma unroll
        for (int t = 0; t < 4; ++t) {
            const unsigned short* vr = Vb + (t * 16 + lan) * 64 + ((quad & 1) << 2);
            #pragma unroll
            for (int nt = 0; nt < 4; ++nt) {
                const int g2 = nt * 2 + (quad >> 1);
                Vfv[t][nt] = *(const bf16x4*)(vr + ((g2 ^ (lan & 7)) << 3));
            }
        }
        if (kt == ch) {   // diagonal: mask k > q
            #pragma unroll
            for (int nt = 0; nt < 4; ++nt)
                #pragma unroll
                for (int reg = 0; reg < 4; ++reg)
                    if (kBase + nt * 16 + quad * 4 + reg > qAbs)
                        scCur[nt][reg] = -INFINITY;
        }
        // softmax on scCur (computed one iter ago -> MFMA long done)
        float mx = scCur[0][0];
        #pragma unroll
        for (int nt = 0; nt < 4; ++nt)
            #pragma unroll
            for (int reg = 0; reg < 4; ++reg) mx = fmaxf(mx, scCur[nt][reg]);
        mx = fmaxf(mx, __shfl_xor(mx, 16, 64));
        mx = fmaxf(mx, __shfl_xor(mx, 32, 64));
        const float mnew = fmaxf(mrow, mx);
        if (!__all(mx <= mrow)) {        // uniform skip: max unchanged on all lanes
            const float alpha = exp2f(mrow - mnew);
            l_acc[0] *= alpha;
            #pragma unroll
            for (int t = 0; t < 4; ++t)
                #pragma unroll
                for (int i = 0; i < 4; ++i) o[t][i] *= alpha;
        }
        mrow = mnew;
        bf16x4 pb[4];
        #pragma unroll
        for (int nt = 0; nt < 4; ++nt)
            #pragma unroll
            for (int reg = 0; reg < 4; ++reg)
                pb[nt][reg] = static_cast<__bf16>(exp2f(scCur[nt][reg] - mnew));
        // l += sum_k P (ones-column MFMAs)
        #pragma unroll
        for (int nt = 0; nt < 4; ++nt)
            l_acc = mfma_pv(ones, pb[nt], l_acc);
        // O^T += V^T . P^T  (V frags already in registers)
        #pragma unroll
        for (int t = 0; t < 4; ++t)
            #pragma unroll
            for (int nt = 0; nt < 4; ++nt)
                o[t] = mfma_pv(Vfv[t][nt], pb[nt], o[t]);
        #pragma unroll
        for (int nt = 0; nt < 4; ++nt) scCur[nt] = scNext[nt];
    }
    const float rl = 1.f / l_acc[0];
    #pragma unroll
    for (int t = 0; t < 4; ++t) {
        bf16x4 ob;
        #pragma unroll
        for (int reg = 0; reg < 4; ++reg)
            ob[reg] = static_cast<__bf16>(o[t][reg] * rl);
        *(bf16x4*)(attn + ((size_t)bn * SS_ + qAbs) * 64 + t * 16 + quad * 4) = ob;
    }
    #undef STAGE_K
    #undef STAGE_V
    #undef QK_TILE
}

// ---------- K3: output projection, m97 GEMM, BM=64 tile (2 blk/CU) ----------
__global__ __launch_bounds__(256) void out_m97_kernel(
    const unsigned short* __restrict__ attn,
    const unsigned short* __restrict__ WOt,
    float* __restrict__ out)
{
    __shared__ unsigned short As[64 * 64];
    __shared__ unsigned short Bs[128 * 64];
    const int tid = threadIdx.x;
    const int l = tid & 63, w = tid >> 6;
    const int quad = l >> 4, lan = l & 15;
    const int mBase = blockIdx.x * 64;
    const int nBase = blockIdx.y * 128;
    const int wm = (w & 1) * 32, wn = (w >> 1) * 64;
    const int bbU = mBase >> 11;
    const int ssBase = mBase & 2047;

    floatx4 acc[2][4];
    #pragma unroll
    for (int a = 0; a < 2; ++a)
        #pragma unroll
        for (int b = 0; b < 4; ++b)
            #pragma unroll
            for (int i = 0; i < 4; ++i) acc[a][b][i] = 0.f;

    const int sr = l >> 3;
    const int sgx = ((l & 7) ^ sr) * 8;

    for (int kt = 0; kt < 16; ++kt) {
        const int k0 = kt * 64;
        __syncthreads();
        #pragma unroll
        for (int i = 0; i < 2; ++i) {
            const int row = i * 32 + w * 8 + sr;
            gl_lds16(attn + ((size_t)(bbU * NH_ + kt) * SS_ + ssBase + row) * 64 + sgx,
                     As + i * 2048 + w * 512);
        }
        #pragma unroll
        for (int i = 0; i < 4; ++i) {
            const int row = i * 32 + w * 8 + sr;
            gl_lds16(WOt + (size_t)(nBase + row) * DD_ + k0 + sgx,
                     Bs + i * 2048 + w * 512);
        }
        __syncthreads();
        #pragma unroll
        for (int ks = 0; ks < 2; ++ks) {
            const int fo = (((ks * 4 + quad) ^ (lan & 7)) << 3);
            bf16x8 a[2], b[4];
            #pragma unroll
            for (int mi = 0; mi < 2; ++mi)
                a[mi] = *(const bf16x8*)(As + (wm + mi * 16 + lan) * 64 + fo);
            #pragma unroll
            for (int ni = 0; ni < 4; ++ni)
                b[ni] = *(const bf16x8*)(Bs + (wn + ni * 16 + lan) * 64 + fo);
            #pragma unroll
            for (int mi = 0; mi < 2; ++mi)
                #pragma unroll
                for (int ni = 0; ni < 4; ++ni)
                    acc[mi][ni] = __builtin_amdgcn_mfma_f32_16x16x32_bf16(
                        a[mi], b[ni], acc[mi][ni], 0, 0, 0);
        }
    }
    #pragma unroll
    for (int mi = 0; mi < 2; ++mi)
        #pragma unroll
        for (int ni = 0; ni < 4; ++ni)
            #pragma unroll
            for (int reg = 0; reg < 4; ++reg) {
                int m = mBase + wm + mi * 16 + quad * 4 + reg;
                out[(size_t)m * DD_ + nBase + wn + ni * 16 + lan] = acc[mi][ni][reg];
            }
}

extern "C" void kernel_launch(void* const* d_in, const int* in_sizes, int n_in,
                              void* d_out, int out_size, void* d_ws, size_t ws_size,
                              hipStream_t stream) {
    const float* resid = (const float*)d_in[0];
    const float* WQ    = (const float*)d_in[1];
    const float* WK    = (const float*)d_in[2];
    const float* WV    = (const float*)d_in[3];
    const float* WO    = (const float*)d_in[4];
    float* out = (float*)d_out;

    unsigned short* q      = (unsigned short*)d_ws;
    unsigned short* kk     = q      + 4194304;
    unsigned short* vT     = kk     + 4194304;
    unsigned short* attn   = vT     + 4194304;
    unsigned short* residB = attn   + 4194304;
    unsigned short* WQb    = residB + 4194304;
    unsigned short* WKb    = WQb    + 1048576;
    unsigned short* WVb    = WKb    + 1048576;
    unsigned short* WOt    = WVb    + 1048576;

    cast_bf16_kernel<<<dim3(7168), 256, 0, stream>>>(
        resid, WQ, WK, WV, residB, WQb, WKb, WVb);
    wo_transpose_kernel<<<dim3(16, 16), 256, 0, stream>>>(WO, WOt);
    qkv_m97_kernel<<<dim3(64, 8, 3), 256, 0, stream>>>(
        residB, WQb, WKb, WVb, q, kk, vT);
    flash_mfma_kernel<<<dim3(1024), dim3(256), 0, stream>>>(q, kk, vT, attn);
    out_m97_kernel<<<dim3(64, 8), 256, 0, stream>>>(attn, WOt, out);
}

// Round 8
// 174.921 us; speedup vs baseline: 1.1661x; 1.0325x over previous
//
#include <hip/hip_runtime.h>
#include <math.h>

// R17: FUSED qkv GEMM — one kernel computes Q,K,V (shared A staging).
// Theory: qkv staging traffic (576 MB at BM=64/BN=128 x3 z) is the cost:
// ~43us at the ~21.7 B/cyc/CU gl_lds fill rate. Fusing the 3 GEMMs over
// shared residB A-tiles at BM=128/BN=64 cuts staged bytes to 320 MB
// (A 128 + B 192) while keeping 2 blk/CU x 8 waves = 16 waves/CU.
// Per-output MFMA k-chain identical -> bitwise-same Q/K/V (absmax 7.8e-3).
// flash (R15 body, 53us), out (R16 BM=64), cast, wo_t: unchanged.
// R16 post-mortem: BM=64 TLP fix won -15us -> non-flash GEMMs confirmed
// latency/staging-bound; flash scheduling theories all dead (R11-R15).
// Layouts (verified R2-R16, absmax 7.8e-3):
//   x32 A-frag: m=lane&15, k=(lane>>4)*8+j ; B-frag: n=lane&15, k=(lane>>4)*8+j
//   x16 A/B-frag: idx=lane&15, k=(lane>>4)*4+j
//   C/D (all 16x16): col=lane&15, row=(lane>>4)*4+reg

#define SS_ 2048
#define DD_ 1024
#define NH_ 16
#define BN_ 32
#define BS_ 4096

typedef __bf16 bf16x8 __attribute__((ext_vector_type(8)));
typedef __bf16 bf16x4 __attribute__((ext_vector_type(4)));
typedef short shortx4 __attribute__((ext_vector_type(4)));
typedef float floatx4 __attribute__((ext_vector_type(4)));
typedef unsigned short ushortx4 __attribute__((ext_vector_type(4)));

__device__ __forceinline__ unsigned short f2bf(float f) {
    union { float f; unsigned u; } v; v.f = f;
    unsigned r = v.u + 0x7FFFu + ((v.u >> 16) & 1u);   // RNE
    return (unsigned short)(r >> 16);
}

__device__ __forceinline__ floatx4 mfma_pv(bf16x4 a, bf16x4 b, floatx4 c) {
#if __has_builtin(__builtin_amdgcn_mfma_f32_16x16x16_bf16)
    return __builtin_amdgcn_mfma_f32_16x16x16_bf16(a, b, c, 0, 0, 0);
#else
    return __builtin_amdgcn_mfma_f32_16x16x16bf16_1k(
        __builtin_bit_cast(shortx4, a), __builtin_bit_cast(shortx4, b), c, 0, 0, 0);
#endif
}

__device__ __forceinline__ void gl_lds16(const unsigned short* g, unsigned short* l) {
    __builtin_amdgcn_global_load_lds(
        (const __attribute__((address_space(1))) unsigned int*)g,
        (__attribute__((address_space(3))) unsigned int*)l, 16, 0, 0);
}

// ---------- K0a: cast resid + WQ/WK/WV to bf16 (1D grid) ----------
__global__ __launch_bounds__(256) void cast_bf16_kernel(
    const float* __restrict__ resid, const float* __restrict__ WQ,
    const float* __restrict__ WK, const float* __restrict__ WV,
    unsigned short* __restrict__ residB, unsigned short* __restrict__ WQb,
    unsigned short* __restrict__ WKb, unsigned short* __restrict__ WVb)
{
    const int x = blockIdx.x;
    int z, ix;
    if (x < 4096) { z = 0; ix = x; }
    else { z = 1 + ((x - 4096) >> 10); ix = (x - 4096) & 1023; }
    const float* src = (z == 0) ? resid : (z == 1) ? WQ : (z == 2) ? WK : WV;
    unsigned short* dst = (z == 0) ? residB : (z == 1) ? WQb : (z == 2) ? WKb : WVb;
    const int i = (ix * 256 + threadIdx.x) * 4;
    float4 f = *(const float4*)(src + i);
    ushortx4 o;
    o[0] = f2bf(f.x); o[1] = f2bf(f.y); o[2] = f2bf(f.z); o[3] = f2bf(f.w);
    *(ushortx4*)(dst + i) = o;
}

// ---------- K0b: WO [kk=n*64+h][d] fp32 -> WOt [d][kk] bf16 ----------
__global__ __launch_bounds__(256) void wo_transpose_kernel(
    const float* __restrict__ WO, unsigned short* __restrict__ WOt)
{
    __shared__ float t[64][65];
    const int kk0 = blockIdx.x * 64, d0 = blockIdx.y * 64;
    #pragma unroll
    for (int it = 0; it < 16; ++it) {
        int idx = it * 256 + threadIdx.x;
        int r = idx >> 6, c = idx & 63;
        t[r][c] = WO[(kk0 + r) * DD_ + d0 + c];
    }
    __syncthreads();
    #pragma unroll
    for (int it = 0; it < 16; ++it) {
        int idx = it * 256 + threadIdx.x;
        int r = idx >> 6, c = idx & 63;
        WOt[(d0 + r) * DD_ + kk0 + c] = f2bf(t[c][r]);
    }
}

// ---------- K1: FUSED QKV projection GEMM (BM=128, BN=64=one head) ----------
// grid (32, 16), 512 thr (8 waves). Wave w owns rows [w*16, w*16+16).
// Shared A-tile (residB) staged once per K-step; 3 B-tiles (WQ/WK/WV head).
// q (head-major [bn][h][s], scale folded), kk ([bn][s][h]), vT ([bn][h][s]).
__global__ __launch_bounds__(512, 4) void qkv_fused_kernel(
    const unsigned short* __restrict__ residB,
    const unsigned short* __restrict__ WQb,
    const unsigned short* __restrict__ WKb,
    const unsigned short* __restrict__ WVb,
    unsigned short* __restrict__ q, unsigned short* __restrict__ kk,
    unsigned short* __restrict__ vT)
{
    __shared__ unsigned short As[128 * 64];
    __shared__ unsigned short Bq[64 * 64];
    __shared__ unsigned short Bk[64 * 64];
    __shared__ unsigned short Bv[64 * 64];
    const int tid = threadIdx.x;
    const int l = tid & 63, w = tid >> 6;          // w: 0..7
    const int quad = l >> 4, lan = l & 15;
    const int mBase = blockIdx.x * 128;
    const int head = blockIdx.y;                   // BN=64 == one head
    const int nBase = head * 64;

    floatx4 accQ[4], accK[4], accV[4];
    #pragma unroll
    for (int ni = 0; ni < 4; ++ni)
        #pragma unroll
        for (int i = 0; i < 4; ++i) {
            accQ[ni][i] = 0.f; accK[ni][i] = 0.f; accV[ni][i] = 0.f;
        }

    const int sr = l >> 3;
    const int sgx = ((l & 7) ^ sr) * 8;

    for (int k0 = 0; k0 < DD_; k0 += 64) {
        __syncthreads();
        // A: 128 rows, wave w stages [w*16, w*16+16) (2x gl_lds16)
        gl_lds16(residB + (size_t)(mBase + w * 16 + sr) * DD_ + k0 + sgx,
                 As + (w * 16) * 64);
        gl_lds16(residB + (size_t)(mBase + w * 16 + 8 + sr) * DD_ + k0 + sgx,
                 As + (w * 16 + 8) * 64);
        // B (each 64 rows): wave w stages rows [w*8, w*8+8) of each weight
        gl_lds16(WQb + (size_t)(nBase + w * 8 + sr) * DD_ + k0 + sgx,
                 Bq + (w * 8) * 64);
        gl_lds16(WKb + (size_t)(nBase + w * 8 + sr) * DD_ + k0 + sgx,
                 Bk + (w * 8) * 64);
        gl_lds16(WVb + (size_t)(nBase + w * 8 + sr) * DD_ + k0 + sgx,
                 Bv + (w * 8) * 64);
        __syncthreads();
        #pragma unroll
        for (int ks = 0; ks < 2; ++ks) {
            const int fo = (((ks * 4 + quad) ^ (lan & 7)) << 3);
            bf16x8 a = *(const bf16x8*)(As + (w * 16 + lan) * 64 + fo);
            bf16x8 bq[4], bk[4], bv[4];
            #pragma unroll
            for (int ni = 0; ni < 4; ++ni) {
                bq[ni] = *(const bf16x8*)(Bq + (ni * 16 + lan) * 64 + fo);
                bk[ni] = *(const bf16x8*)(Bk + (ni * 16 + lan) * 64 + fo);
                bv[ni] = *(const bf16x8*)(Bv + (ni * 16 + lan) * 64 + fo);
            }
            #pragma unroll
            for (int ni = 0; ni < 4; ++ni) {
                accQ[ni] = __builtin_amdgcn_mfma_f32_16x16x32_bf16(a, bq[ni], accQ[ni], 0, 0, 0);
                accK[ni] = __builtin_amdgcn_mfma_f32_16x16x32_bf16(a, bk[ni], accK[ni], 0, 0, 0);
                accV[ni] = __builtin_amdgcn_mfma_f32_16x16x32_bf16(a, bv[ni], accV[ni], 0, 0, 0);
            }
        }
    }
    // epilogue: rows m0..m0+3 contiguous (same bb; ss0 multiple of 4)
    const int m0 = mBase + w * 16 + quad * 4;
    const int bb = m0 >> 11, ss0 = m0 & 2047;
    const float scl = 0.125f * 1.44269504088896340736f;
    #pragma unroll
    for (int ni = 0; ni < 4; ++ni) {
        const int h = ni * 16 + lan;
        bf16x4 obq, obv;
        #pragma unroll
        for (int reg = 0; reg < 4; ++reg) {
            obq[reg] = static_cast<__bf16>(accQ[ni][reg] * scl);
            obv[reg] = static_cast<__bf16>(accV[ni][reg]);
        }
        *(bf16x4*)(q  + ((size_t)(bb * NH_ + head) * 64 + h) * SS_ + ss0) = obq;
        *(bf16x4*)(vT + ((size_t)(bb * NH_ + head) * 64 + h) * SS_ + ss0) = obv;
        #pragma unroll
        for (int reg = 0; reg < 4; ++reg)
            kk[((size_t)(bb * NH_ + head) * SS_ + ss0 + reg) * 64 + h] =
                f2bf(accK[ni][reg]);
    }
}

// ---------- K2: flash attention (R15 body, untouched) ----------
__global__ __launch_bounds__(256, 4) void flash_mfma_kernel(
    const unsigned short* __restrict__ q,
    const unsigned short* __restrict__ k,
    const unsigned short* __restrict__ vT,
    unsigned short* __restrict__ attn)
{
    __shared__ unsigned short ldsK[3][64 * 64];   // triple: QK runs one ahead
    __shared__ unsigned short ldsV[2][64 * 64];
    const int l = threadIdx.x & 63, w = threadIdx.x >> 6;   // w: 0..3
    const int quad = l >> 4, lan = l & 15;
    const int f = blockIdx.x;                               // 0..1023
    const int bn = (f & 7) | (((f >> 3) & 3) << 3);         // XCD swizzle
    const int g = f >> 5;                                   // 0..31
    const int ch = (g < 8) ? (31 - g)
                 : (g < 16) ? (g + 8)
                 : (g < 24) ? (15 - (g - 16))
                 : (g - 24);

    const unsigned short* Qg = q  + (size_t)bn * 64 * SS_;  // [h][s]
    const unsigned short* Kg = k  + (size_t)bn * SS_ * 64;  // [s][h]
    const unsigned short* Vg = vT + (size_t)bn * 64 * SS_;  // [h][s]

    const int srl = l >> 3;
    const int sgx = (l & 7) ^ srl;

    const int qRow0 = ch * 64 + w * 16;
    const int qAbs = qRow0 + lan;

    // Q from [h][s]: 16 strided scalar loads, once per block (cheap)
    bf16x8 Qf0, Qf1;
    #pragma unroll
    for (int j = 0; j < 8; ++j) {
        Qf0[j] = *(const __bf16*)(Qg + (size_t)(quad * 8 + j) * SS_ + qAbs);
        Qf1[j] = *(const __bf16*)(Qg + (size_t)(quad * 8 + j + 32) * SS_ + qAbs);
    }

    bf16x4 ones;
    #pragma unroll
    for (int i = 0; i < 4; ++i) ones[i] = static_cast<__bf16>(1.0f);

    float mrow = -INFINITY;
    floatx4 l_acc;                       // only [0] kept consistent
    floatx4 o[4];
    #pragma unroll
    for (int i = 0; i < 4; ++i) l_acc[i] = 0.f;
    #pragma unroll
    for (int t = 0; t < 4; ++t)
        #pragma unroll
        for (int i = 0; i < 4; ++i) o[t][i] = 0.f;

    #define STAGE_K(kt_, buf_)                                                  \
        { const int row0_ = w * 16, kB_ = (kt_) * 64;                           \
          gl_lds16(Kg + (size_t)(kB_ + row0_ + srl) * 64 + sgx * 8,             \
                   &ldsK[buf_][row0_ * 64]);                                    \
          gl_lds16(Kg + (size_t)(kB_ + row0_ + 8 + srl) * 64 + sgx * 8,         \
                   &ldsK[buf_][(row0_ + 8) * 64]); }
    #define STAGE_V(kt_, buf_)                                                  \
        { const int row0_ = w * 16, kB_ = (kt_) * 64;                           \
          gl_lds16(Vg + (size_t)(row0_ + srl) * SS_ + kB_ + sgx * 8,            \
                   &ldsV[buf_][row0_ * 64]);                                    \
          gl_lds16(Vg + (size_t)(row0_ + 8 + srl) * SS_ + kB_ + sgx * 8,        \
                   &ldsV[buf_][(row0_ + 8) * 64]); }
    #define QK_TILE(dst_, buf_)                                                 \
        { const unsigned short* Kb_ = &ldsK[buf_][0];                           \
          bf16x8 K0v_[4], K1v_[4];                                              \
          _Pragma("unroll")                                                     \
          for (int nt = 0; nt < 4; ++nt) {                                      \
              const unsigned short* kr_ = Kb_ + (nt * 16 + lan) * 64;           \
              K0v_[nt] = *(const bf16x8*)(kr_ + ((quad ^ (lan & 7)) << 3));     \
              K1v_[nt] = *(const bf16x8*)(kr_ + (((quad + 4) ^ (lan & 7)) << 3)); } \
          _Pragma("unroll")                                                     \
          for (int nt = 0; nt < 4; ++nt) {                                      \
              floatx4 zz_; zz_[0] = zz_[1] = zz_[2] = zz_[3] = 0.f;             \
              dst_[nt] = __builtin_amdgcn_mfma_f32_16x16x32_bf16(K0v_[nt], Qf0, zz_, 0, 0, 0); \
              dst_[nt] = __builtin_amdgcn_mfma_f32_16x16x32_bf16(K1v_[nt], Qf1, dst_[nt], 0, 0, 0); } }

    // prologue: stage(0); barrier; stage K(1); scCur = QK(0)
    STAGE_K(0, 0);
    STAGE_V(0, 0);
    __syncthreads();
    if (ch >= 1) STAGE_K(1, 1);
    floatx4 scCur[4], scNext[4];
    QK_TILE(scCur, 0);

    for (int kt = 0; kt <= ch; ++kt) {
        const int kBase = kt * 64;
        __syncthreads();   // stage(kt+1) visible; prior readers drained
        if (kt + 2 <= ch) STAGE_K(kt + 2, (kt + 2) % 3);
        if (kt + 1 <= ch) {
            STAGE_V(kt + 1, (kt + 1) & 1);
            QK_TILE(scNext, (kt + 1) % 3);   // issue next QK before softmax
        }
        // batched V reads for THIS tile: latency hides under softmax VALU
        const unsigned short* Vb = &ldsV[kt & 1][0];
        bf16x4 Vfv[4][4];
        #pragma unroll
        for (int t = 0; t < 4; ++t) {
            const unsigned short* vr = Vb + (t * 16 + lan) * 64 + ((quad & 1) << 2);
            #pragma unroll
            for (int nt = 0; nt < 4; ++nt) {
                const int g2 = nt * 2 + (quad >> 1);
                Vfv[t][nt] = *(const bf16x4*)(vr + ((g2 ^ (lan & 7)) << 3));
            }
        }
        if (kt == ch) {   // diagonal: mask k > q
            #pragma unroll
            for (int nt = 0; nt < 4; ++nt)
                #pragma unroll
                for (int reg = 0; reg < 4; ++reg)
                    if (kBase + nt * 16 + quad * 4 + reg > qAbs)
                        scCur[nt][reg] = -INFINITY;
        }
        // softmax on scCur (computed one iter ago -> MFMA long done)
        float mx = scCur[0][0];
        #pragma unroll
        for (int nt = 0; nt < 4; ++nt)
            #pragma unroll
            for (int reg = 0; reg < 4; ++reg) mx = fmaxf(mx, scCur[nt][reg]);
        mx = fmaxf(mx, __shfl_xor(mx, 16, 64));
        mx = fmaxf(mx, __shfl_xor(mx, 32, 64));
        const float mnew = fmaxf(mrow, mx);
        if (!__all(mx <= mrow)) {        // uniform skip: max unchanged on all lanes
            const float alpha = exp2f(mrow - mnew);
            l_acc[0] *= alpha;
            #pragma unroll
            for (int t = 0; t < 4; ++t)
                #pragma unroll
                for (int i = 0; i < 4; ++i) o[t][i] *= alpha;
        }
        mrow = mnew;
        bf16x4 pb[4];
        #pragma unroll
        for (int nt = 0; nt < 4; ++nt)
            #pragma unroll
            for (int reg = 0; reg < 4; ++reg)
                pb[nt][reg] = static_cast<__bf16>(exp2f(scCur[nt][reg] - mnew));
        // l += sum_k P (ones-column MFMAs)
        #pragma unroll
        for (int nt = 0; nt < 4; ++nt)
            l_acc = mfma_pv(ones, pb[nt], l_acc);
        // O^T += V^T . P^T  (V frags already in registers)
        #pragma unroll
        for (int t = 0; t < 4; ++t)
            #pragma unroll
            for (int nt = 0; nt < 4; ++nt)
                o[t] = mfma_pv(Vfv[t][nt], pb[nt], o[t]);
        #pragma unroll
        for (int nt = 0; nt < 4; ++nt) scCur[nt] = scNext[nt];
    }
    const float rl = 1.f / l_acc[0];
    #pragma unroll
    for (int t = 0; t < 4; ++t) {
        bf16x4 ob;
        #pragma unroll
        for (int reg = 0; reg < 4; ++reg)
            ob[reg] = static_cast<__bf16>(o[t][reg] * rl);
        *(bf16x4*)(attn + ((size_t)bn * SS_ + qAbs) * 64 + t * 16 + quad * 4) = ob;
    }
    #undef STAGE_K
    #undef STAGE_V
    #undef QK_TILE
}

// ---------- K3: output projection, m97 GEMM, BM=64 tile (2 blk/CU) ----------
__global__ __launch_bounds__(256) void out_m97_kernel(
    const unsigned short* __restrict__ attn,
    const unsigned short* __restrict__ WOt,
    float* __restrict__ out)
{
    __shared__ unsigned short As[64 * 64];
    __shared__ unsigned short Bs[128 * 64];
    const int tid = threadIdx.x;
    const int l = tid & 63, w = tid >> 6;
    const int quad = l >> 4, lan = l & 15;
    const int mBase = blockIdx.x * 64;
    const int nBase = blockIdx.y * 128;
    const int wm = (w & 1) * 32, wn = (w >> 1) * 64;
    const int bbU = mBase >> 11;
    const int ssBase = mBase & 2047;

    floatx4 acc[2][4];
    #pragma unroll
    for (int a = 0; a < 2; ++a)
        #pragma unroll
        for (int b = 0; b < 4; ++b)
            #pragma unroll
            for (int i = 0; i < 4; ++i) acc[a][b][i] = 0.f;

    const int sr = l >> 3;
    const int sgx = ((l & 7) ^ sr) * 8;

    for (int kt = 0; kt < 16; ++kt) {
        const int k0 = kt * 64;
        __syncthreads();
        #pragma unroll
        for (int i = 0; i < 2; ++i) {
            const int row = i * 32 + w * 8 + sr;
            gl_lds16(attn + ((size_t)(bbU * NH_ + kt) * SS_ + ssBase + row) * 64 + sgx,
                     As + i * 2048 + w * 512);
        }
        #pragma unroll
        for (int i = 0; i < 4; ++i) {
            const int row = i * 32 + w * 8 + sr;
            gl_lds16(WOt + (size_t)(nBase + row) * DD_ + k0 + sgx,
                     Bs + i * 2048 + w * 512);
        }
        __syncthreads();
        #pragma unroll
        for (int ks = 0; ks < 2; ++ks) {
            const int fo = (((ks * 4 + quad) ^ (lan & 7)) << 3);
            bf16x8 a[2], b[4];
            #pragma unroll
            for (int mi = 0; mi < 2; ++mi)
                a[mi] = *(const bf16x8*)(As + (wm + mi * 16 + lan) * 64 + fo);
            #pragma unroll
            for (int ni = 0; ni < 4; ++ni)
                b[ni] = *(const bf16x8*)(Bs + (wn + ni * 16 + lan) * 64 + fo);
            #pragma unroll
            for (int mi = 0; mi < 2; ++mi)
                #pragma unroll
                for (int ni = 0; ni < 4; ++ni)
                    acc[mi][ni] = __builtin_amdgcn_mfma_f32_16x16x32_bf16(
                        a[mi], b[ni], acc[mi][ni], 0, 0, 0);
        }
    }
    #pragma unroll
    for (int mi = 0; mi < 2; ++mi)
        #pragma unroll
        for (int ni = 0; ni < 4; ++ni)
            #pragma unroll
            for (int reg = 0; reg < 4; ++reg) {
                int m = mBase + wm + mi * 16 + quad * 4 + reg;
                out[(size_t)m * DD_ + nBase + wn + ni * 16 + lan] = acc[mi][ni][reg];
            }
}

extern "C" void kernel_launch(void* const* d_in, const int* in_sizes, int n_in,
                              void* d_out, int out_size, void* d_ws, size_t ws_size,
                              hipStream_t stream) {
    const float* resid = (const float*)d_in[0];
    const float* WQ    = (const float*)d_in[1];
    const float* WK    = (const float*)d_in[2];
    const float* WV    = (const float*)d_in[3];
    const float* WO    = (const float*)d_in[4];
    float* out = (float*)d_out;

    unsigned short* q      = (unsigned short*)d_ws;
    unsigned short* kk     = q      + 4194304;
    unsigned short* vT     = kk     + 4194304;
    unsigned short* attn   = vT     + 4194304;
    unsigned short* residB = attn   + 4194304;
    unsigned short* WQb    = residB + 4194304;
    unsigned short* WKb    = WQb    + 1048576;
    unsigned short* WVb    = WKb    + 1048576;
    unsigned short* WOt    = WVb    + 1048576;

    cast_bf16_kernel<<<dim3(7168), 256, 0, stream>>>(
        resid, WQ, WK, WV, residB, WQb, WKb, WVb);
    wo_transpose_kernel<<<dim3(16, 16), 256, 0, stream>>>(WO, WOt);
    qkv_fused_kernel<<<dim3(32, 16), 512, 0, stream>>>(
        residB, WQb, WKb, WVb, q, kk, vT);
    flash_mfma_kernel<<<dim3(1024), dim3(256), 0, stream>>>(q, kk, vT, attn);
    out_m97_kernel<<<dim3(64, 8), 256, 0, stream>>>(attn, WOt, out);
}